// Round 3
// baseline (228.938 us; speedup 1.0000x reference)
//
#include <hip/hip_runtime.h>

#define SEQ 2048
#define DD 128
#define HQ 32
#define HKV 8
#define WIN 512
#define QT 32

typedef unsigned short u16;
typedef unsigned int u32;
typedef __attribute__((ext_vector_type(8))) short bf16x8;
typedef __attribute__((ext_vector_type(4))) float f32x4;

__device__ __forceinline__ u16 f2bf(float f) {
  u32 u = __builtin_bit_cast(u32, f);
  u += 0x7FFFu + ((u >> 16) & 1u);
  return (u16)(u >> 16);
}

__device__ __forceinline__ u32 cvtpk(float lo, float hi) {
  u32 r;
  asm("v_cvt_pk_bf16_f32 %0, %1, %2" : "=v"(r) : "v"(lo), "v"(hi));
  return r;
}

// GroupRMSNorm + weight + scale fold + bf16 + repack to [b][h][s][d]
__device__ __forceinline__ void norm_body(
    const float* __restrict__ x, const float* __restrict__ w,
    u16* __restrict__ o, int hshift, float scale, int blk, int tid) {
  const int lane = tid & 63;
  const int wv = tid >> 6;
  const int sub = lane >> 5;
  const int l5 = lane & 31;
  const int rid = blk * 8 + wv * 2 + sub;   // flattened (b,s,h)
  const int H = 1 << hshift;
  const int hh = rid & (H - 1);
  const int s = (rid >> hshift) & (SEQ - 1);
  const int b = rid >> (hshift + 11);
  const float4 xv = *(reinterpret_cast<const float4*>(x + (size_t)rid * DD) + l5);
  float ssq = xv.x * xv.x + xv.y * xv.y + xv.z * xv.z + xv.w * xv.w;
  ssq += __shfl_xor(ssq, 1);
  ssq += __shfl_xor(ssq, 2);
  ssq += __shfl_xor(ssq, 4);
  ssq += __shfl_xor(ssq, 8);
  ssq += __shfl_xor(ssq, 16);
  const float inv = rsqrtf(ssq * (1.0f / 128.0f) + 1e-5f) * scale;
  const float4 wv4 = *(reinterpret_cast<const float4*>(w + hh * DD) + l5);
  const u16 o0 = f2bf(xv.x * inv * wv4.x);
  const u16 o1 = f2bf(xv.y * inv * wv4.y);
  const u16 o2 = f2bf(xv.z * inv * wv4.z);
  const u16 o3 = f2bf(xv.w * inv * wv4.w);
  const size_t oo = (((size_t)b * H + hh) * SEQ + s) * DD + l5 * 4;
  uint2 pk;
  pk.x = (u32)o0 | ((u32)o1 << 16);
  pk.y = (u32)o2 | ((u32)o3 << 16);
  *reinterpret_cast<uint2*>(o + oo) = pk;
}

// V: fp32 [b][s][h][d] -> bf16 transposed [b][h][d][s]
__device__ __forceinline__ void transv_body(
    const float* __restrict__ v, u16* __restrict__ vt, int bid, int t) {
  const int st = bid & 31;
  const int h = (bid >> 5) & 7;
  const int b = bid >> 8;
  const int sbase = st * 64;
  const int d = t & 127;
  const int sch = (t >> 7) * 32;
  const size_t oo = (((size_t)(b * HKV + h)) * DD + d) * SEQ + sbase + sch;
#pragma unroll
  for (int q8 = 0; q8 < 4; ++q8) {
    uint4 o;
    u32 c[4];
#pragma unroll
    for (int p = 0; p < 4; ++p) {
      const int ss0 = q8 * 8 + p * 2;
      const int s0 = sbase + sch + ss0;
      const float a0 = v[((size_t)(b * SEQ + s0) * HKV + h) * DD + d];
      const float a1 = v[((size_t)(b * SEQ + s0 + 1) * HKV + h) * DD + d];
      c[p] = (u32)f2bf(a0) | ((u32)f2bf(a1) << 16);
    }
    o.x = c[0]; o.y = c[1]; o.z = c[2]; o.w = c[3];
    *reinterpret_cast<uint4*>(vt + oo + q8 * 8) = o;
  }
}

__global__ void __launch_bounds__(256) prep_kernel(
    const float* __restrict__ q, const float* __restrict__ k,
    const float* __restrict__ v, const float* __restrict__ qw,
    const float* __restrict__ kw, u16* __restrict__ qn,
    u16* __restrict__ kn, u16* __restrict__ vt) {
  const int blk = blockIdx.x;
  const int tid = threadIdx.x;
  if (blk < 16384) {
    norm_body(q, qw, qn, 5, 0.08838834764831845f, blk, tid);
  } else if (blk < 20480) {
    norm_body(k, kw, kn, 3, 1.0f, blk - 16384, tid);
  } else {
    transv_body(v, vt, blk - 20480, tid);
  }
}

__global__ void __launch_bounds__(256) attn_kernel(
    const u16* __restrict__ qn, const u16* __restrict__ kn,
    const u16* __restrict__ vt, float* __restrict__ out) {
  const int tid = threadIdx.x;
  const int w = tid >> 6;
  const int lane = tid & 63;
  const int c = lane & 15;
  const int g = lane >> 4;

  // XCD-locality remap: each XCD owns 128 consecutive logical blocks
  // = 2 full (b,hk) K/V strips (~1.2MB, L2-resident).
  const int p = blockIdx.x;
  const int bid = ((p & 7) << 7) + (p >> 3);
  const int qt = bid & 63;
  const int hk = (bid >> 6) & 7;
  const int b = bid >> 9;
  const int i0 = qt * QT;
  const int h = hk * 4 + w;

  const u16* qb = qn + ((size_t)(b * HQ + h) * SEQ + i0) * DD;
  // per-lane base pointers: K fragment (row = s, 16B chunk g), V fragment
  const u16* kl = kn + (size_t)(b * HKV + hk) * SEQ * DD + c * DD + g * 8;
  const u16* vl = vt + (size_t)(b * HKV + hk) * DD * SEQ + c * SEQ + g * 8;

  // Q fragments (MFMA B operand): col=c (query), k=g*8+j
  bf16x8 aq[2][4];
#pragma unroll
  for (int mt = 0; mt < 2; ++mt)
#pragma unroll
    for (int kt = 0; kt < 4; ++kt)
      aq[mt][kt] = *reinterpret_cast<const bf16x8*>(qb + (mt * 16 + c) * DD + kt * 32 + g * 8);

  int ks = i0 - WIN;
  ks = (ks < 0) ? 0 : (ks & ~63);
  const int ntl = (i0 + QT - ks + 63) >> 6;

  const float C_T = 3.70370370e-4f;       // 1/(3*CAP^2)
  const float LOG2E = 1.44269504088896f;
  const float C_E = 43.2808512266689f;    // CAP*log2(e)

  float lsum[2] = {0.0f, 0.0f};

  // ---------------- pass 1: row sums of exp(capped_score - CAP) ----------------
  for (int t = 0; t < ntl; ++t) {
    const int kb = ks + t * 64;
    const u16* kt0 = kl + (size_t)kb * DD;

    f32x4 sc[2][4] = {};
#pragma unroll
    for (int nt = 0; nt < 4; ++nt) {
      const int jb = kb + nt * 16;
      if (jb > i0 + 31 || jb + 15 < i0 - WIN) continue;  // wave-uniform skip
      const bf16x8 b0 = *reinterpret_cast<const bf16x8*>(kt0 + nt * 16 * DD);
      const bf16x8 b1 = *reinterpret_cast<const bf16x8*>(kt0 + nt * 16 * DD + 32);
      const bf16x8 b2 = *reinterpret_cast<const bf16x8*>(kt0 + nt * 16 * DD + 64);
      const bf16x8 b3 = *reinterpret_cast<const bf16x8*>(kt0 + nt * 16 * DD + 96);
      sc[0][nt] = __builtin_amdgcn_mfma_f32_16x16x32_bf16(b0, aq[0][0], sc[0][nt], 0, 0, 0);
      sc[1][nt] = __builtin_amdgcn_mfma_f32_16x16x32_bf16(b0, aq[1][0], sc[1][nt], 0, 0, 0);
      sc[0][nt] = __builtin_amdgcn_mfma_f32_16x16x32_bf16(b1, aq[0][1], sc[0][nt], 0, 0, 0);
      sc[1][nt] = __builtin_amdgcn_mfma_f32_16x16x32_bf16(b1, aq[1][1], sc[1][nt], 0, 0, 0);
      sc[0][nt] = __builtin_amdgcn_mfma_f32_16x16x32_bf16(b2, aq[0][2], sc[0][nt], 0, 0, 0);
      sc[1][nt] = __builtin_amdgcn_mfma_f32_16x16x32_bf16(b2, aq[1][2], sc[1][nt], 0, 0, 0);
      sc[0][nt] = __builtin_amdgcn_mfma_f32_16x16x32_bf16(b3, aq[0][3], sc[0][nt], 0, 0, 0);
      sc[1][nt] = __builtin_amdgcn_mfma_f32_16x16x32_bf16(b3, aq[1][3], sc[1][nt], 0, 0, 0);
    }

#pragma unroll
    for (int mt = 0; mt < 2; ++mt) {
      const int imin = i0 + mt * 16;
      const int i = imin + c;
#pragma unroll
      for (int nt = 0; nt < 4; ++nt) {
        const int jb = kb + nt * 16;
        if (jb > imin + 15 || jb + 15 < imin - WIN) continue;
        const bool needmask = (jb + 15 > imin) || (jb < imin + 15 - WIN);
        const int difg = i - jb - g * 4;   // i - j for r=0
#pragma unroll
        for (int r = 0; r < 4; ++r) {
          const float x = sc[mt][nt][r];
          const float u = fmaf(x * x * (-C_T), x, x);   // 30*tanh(x/30) cubic
          float e = __builtin_amdgcn_exp2f(fmaf(u, LOG2E, -C_E));
          if (needmask) e = ((u32)(difg - r) <= WIN) ? e : 0.0f;
          lsum[mt] += e;
        }
      }
    }
  }

  float ar[2];
#pragma unroll
  for (int mt = 0; mt < 2; ++mt) {
    float l = lsum[mt];
    l += __shfl_xor(l, 16);
    l += __shfl_xor(l, 32);
    ar[mt] = 1.06f / l;
  }

  f32x4 acc[2][8] = {};

  // ---------------- pass 2: recompute scores, clip(probs), PV ----------------
  for (int t = 0; t < ntl; ++t) {
    const int kb = ks + t * 64;
    const u16* kt0 = kl + (size_t)kb * DD;

    f32x4 sc[2][4] = {};
#pragma unroll
    for (int nt = 0; nt < 4; ++nt) {
      const int jb = kb + nt * 16;
      if (jb > i0 + 31 || jb + 15 < i0 - WIN) continue;
      const bf16x8 b0 = *reinterpret_cast<const bf16x8*>(kt0 + nt * 16 * DD);
      const bf16x8 b1 = *reinterpret_cast<const bf16x8*>(kt0 + nt * 16 * DD + 32);
      const bf16x8 b2 = *reinterpret_cast<const bf16x8*>(kt0 + nt * 16 * DD + 64);
      const bf16x8 b3 = *reinterpret_cast<const bf16x8*>(kt0 + nt * 16 * DD + 96);
      sc[0][nt] = __builtin_amdgcn_mfma_f32_16x16x32_bf16(b0, aq[0][0], sc[0][nt], 0, 0, 0);
      sc[1][nt] = __builtin_amdgcn_mfma_f32_16x16x32_bf16(b0, aq[1][0], sc[1][nt], 0, 0, 0);
      sc[0][nt] = __builtin_amdgcn_mfma_f32_16x16x32_bf16(b1, aq[0][1], sc[0][nt], 0, 0, 0);
      sc[1][nt] = __builtin_amdgcn_mfma_f32_16x16x32_bf16(b1, aq[1][1], sc[1][nt], 0, 0, 0);
      sc[0][nt] = __builtin_amdgcn_mfma_f32_16x16x32_bf16(b2, aq[0][2], sc[0][nt], 0, 0, 0);
      sc[1][nt] = __builtin_amdgcn_mfma_f32_16x16x32_bf16(b2, aq[1][2], sc[1][nt], 0, 0, 0);
      sc[0][nt] = __builtin_amdgcn_mfma_f32_16x16x32_bf16(b3, aq[0][3], sc[0][nt], 0, 0, 0);
      sc[1][nt] = __builtin_amdgcn_mfma_f32_16x16x32_bf16(b3, aq[1][3], sc[1][nt], 0, 0, 0);
    }

    // probs -> packed bf16 pairs, in-register
    u32 pk[2][4][2];
#pragma unroll
    for (int mt = 0; mt < 2; ++mt) {
      const int imin = i0 + mt * 16;
      const int i = imin + c;
#pragma unroll
      for (int nt = 0; nt < 4; ++nt) {
        const int jb = kb + nt * 16;
        const bool inval = (jb > imin + 15) || (jb + 15 < imin - WIN);
        const bool needmask = (jb + 15 > imin) || (jb < imin + 15 - WIN);
        const int difg = i - jb - g * 4;
        float pv4[4];
#pragma unroll
        for (int r = 0; r < 4; ++r) {
          float e;
          if (inval) {
            e = 0.0f;
          } else {
            const float x = sc[mt][nt][r];
            const float u = fmaf(x * x * (-C_T), x, x);
            e = __builtin_amdgcn_exp2f(fmaf(u, LOG2E, -C_E));
            if (needmask) e = ((u32)(difg - r) <= WIN) ? e : 0.0f;
          }
          float pp = fmaf(e, ar[mt], -0.03f);
          pv4[r] = fminf(fmaxf(pp, 0.0f), 1.0f);
        }
        pk[mt][nt][0] = cvtpk(pv4[0], pv4[1]);
        pk[mt][nt][1] = cvtpk(pv4[2], pv4[3]);
      }
    }

    // exchange: build PV A-fragments via permlane swaps (no LDS).
    // pf[u] at (c,g) = pk[2k2 + (g>>1)][u&1] @ group (2g+(u>>1))&3
    union PU { bf16x8 v; u32 w4[4]; };
    PU pf[2][2];
#pragma unroll
    for (int mt = 0; mt < 2; ++mt)
#pragma unroll
      for (int k2 = 0; k2 < 2; ++k2) {
        u32 x0 = pk[mt][2 * k2][0], y0 = pk[mt][2 * k2 + 1][0];
        asm("v_permlane32_swap_b32 %0, %1" : "+v"(x0), "+v"(y0));
        asm("v_permlane16_swap_b32 %0, %1" : "+v"(x0), "+v"(y0));
        u32 x1 = pk[mt][2 * k2][1], y1 = pk[mt][2 * k2 + 1][1];
        asm("v_permlane32_swap_b32 %0, %1" : "+v"(x1), "+v"(y1));
        asm("v_permlane16_swap_b32 %0, %1" : "+v"(x1), "+v"(y1));
        pf[mt][k2].w4[0] = x0;
        pf[mt][k2].w4[1] = x1;
        pf[mt][k2].w4[2] = y0;
        pf[mt][k2].w4[3] = y1;
      }

    const u16* vt0 = vl + kb;
#pragma unroll
    for (int dt = 0; dt < 8; ++dt) {
      const bf16x8 bv0 = *reinterpret_cast<const bf16x8*>(vt0 + dt * 16 * SEQ);
      const bf16x8 bv1 = *reinterpret_cast<const bf16x8*>(vt0 + dt * 16 * SEQ + 32);
      acc[0][dt] = __builtin_amdgcn_mfma_f32_16x16x32_bf16(pf[0][0].v, bv0, acc[0][dt], 0, 0, 0);
      acc[1][dt] = __builtin_amdgcn_mfma_f32_16x16x32_bf16(pf[1][0].v, bv0, acc[1][dt], 0, 0, 0);
      acc[0][dt] = __builtin_amdgcn_mfma_f32_16x16x32_bf16(pf[0][1].v, bv1, acc[0][dt], 0, 0, 0);
      acc[1][dt] = __builtin_amdgcn_mfma_f32_16x16x32_bf16(pf[1][1].v, bv1, acc[1][dt], 0, 0, 0);
    }
  }

  // epilogue: out[b][i][h][d] fp32; query = i0+16mt+4g+r, dim = 16dt+c
#pragma unroll
  for (int mt = 0; mt < 2; ++mt)
#pragma unroll
    for (int r = 0; r < 4; ++r) {
      const int i = i0 + mt * 16 + g * 4 + r;
      float* op = out + (((size_t)b * SEQ + i) * HQ + h) * DD + c;
#pragma unroll
      for (int dt = 0; dt < 8; ++dt) op[dt * 16] = acc[mt][dt][r];
    }
}

extern "C" void kernel_launch(void* const* d_in, const int* in_sizes, int n_in,
                              void* d_out, int out_size, void* d_ws, size_t ws_size,
                              hipStream_t stream) {
  const float* q = (const float*)d_in[0];
  const float* k = (const float*)d_in[1];
  const float* v = (const float*)d_in[2];
  const float* qw = (const float*)d_in[3];
  const float* kw = (const float*)d_in[4];
  float* out = (float*)d_out;

  u16* qn = (u16*)d_ws;                                  // [2][32][2048][128] bf16
  u16* kn = qn + (size_t)2 * HQ * SEQ * DD;              // [2][8][2048][128] bf16
  u16* vt = kn + (size_t)2 * HKV * SEQ * DD;             // [2][8][128][2048] bf16

  prep_kernel<<<20992, 256, 0, stream>>>(q, k, v, qw, kw, qn, kn, vt);
  attn_kernel<<<1024, 256, 0, stream>>>(qn, kn, vt, out);
}

// Round 5
// 133.164 us; speedup vs baseline: 1.7192x; 1.7192x over previous
//
#include <hip/hip_runtime.h>

#define SEQ 2048
#define DD 128
#define HQ 32
#define HKV 8
#define WIN 512
#define QT 32

typedef unsigned short u16;
typedef unsigned int u32;
typedef __attribute__((ext_vector_type(8))) short bf16x8;
typedef __attribute__((ext_vector_type(4))) float f32x4;

#define SBAR() asm volatile("s_barrier" ::: "memory")
#define WAITV0() asm volatile("s_waitcnt vmcnt(0)" ::: "memory")
#define WAITV4() asm volatile("s_waitcnt vmcnt(4)" ::: "memory")

__device__ __forceinline__ u16 f2bf(float f) {
  u32 u = __builtin_bit_cast(u32, f);
  u += 0x7FFFu + ((u >> 16) & 1u);
  return (u16)(u >> 16);
}

__device__ __forceinline__ void gl16(const void* g, void* l) {
  __builtin_amdgcn_global_load_lds(
      (const __attribute__((address_space(1))) void*)g,
      (__attribute__((address_space(3))) void*)l, 16, 0, 0);
}

__device__ __forceinline__ u32 cvtpk(float lo, float hi) {
  u32 r;
  asm("v_cvt_pk_bf16_f32 %0, %1, %2" : "=v"(r) : "v"(lo), "v"(hi));
  return r;
}

// GroupRMSNorm + weight + scale fold + bf16 + repack to [b][h][s][d]
__device__ __forceinline__ void norm_body(
    const float* __restrict__ x, const float* __restrict__ w,
    u16* __restrict__ o, int hshift, float scale, int blk, int tid) {
  const int lane = tid & 63;
  const int wv = tid >> 6;
  const int sub = lane >> 5;
  const int l5 = lane & 31;
  const int rid = blk * 8 + wv * 2 + sub;   // flattened (b,s,h)
  const int H = 1 << hshift;
  const int hh = rid & (H - 1);
  const int s = (rid >> hshift) & (SEQ - 1);
  const int b = rid >> (hshift + 11);
  const float4 xv = *(reinterpret_cast<const float4*>(x + (size_t)rid * DD) + l5);
  float ssq = xv.x * xv.x + xv.y * xv.y + xv.z * xv.z + xv.w * xv.w;
  ssq += __shfl_xor(ssq, 1);
  ssq += __shfl_xor(ssq, 2);
  ssq += __shfl_xor(ssq, 4);
  ssq += __shfl_xor(ssq, 8);
  ssq += __shfl_xor(ssq, 16);
  const float inv = rsqrtf(ssq * (1.0f / 128.0f) + 1e-5f) * scale;
  const float4 wv4 = *(reinterpret_cast<const float4*>(w + hh * DD) + l5);
  const u16 o0 = f2bf(xv.x * inv * wv4.x);
  const u16 o1 = f2bf(xv.y * inv * wv4.y);
  const u16 o2 = f2bf(xv.z * inv * wv4.z);
  const u16 o3 = f2bf(xv.w * inv * wv4.w);
  const size_t oo = (((size_t)b * H + hh) * SEQ + s) * DD + l5 * 4;
  uint2 pk;
  pk.x = (u32)o0 | ((u32)o1 << 16);
  pk.y = (u32)o2 | ((u32)o3 << 16);
  *reinterpret_cast<uint2*>(o + oo) = pk;
}

// V: fp32 [b][s][h][d] -> bf16 transposed [b][h][d][s]
__device__ __forceinline__ void transv_body(
    const float* __restrict__ v, u16* __restrict__ vt, int bid, int t) {
  const int st = bid & 31;
  const int h = (bid >> 5) & 7;
  const int b = bid >> 8;
  const int sbase = st * 64;
  const int d = t & 127;
  const int sch = (t >> 7) * 32;
  const size_t oo = (((size_t)(b * HKV + h)) * DD + d) * SEQ + sbase + sch;
#pragma unroll
  for (int q8 = 0; q8 < 4; ++q8) {
    uint4 o;
    u32 c[4];
#pragma unroll
    for (int p = 0; p < 4; ++p) {
      const int ss0 = q8 * 8 + p * 2;
      const int s0 = sbase + sch + ss0;
      const float a0 = v[((size_t)(b * SEQ + s0) * HKV + h) * DD + d];
      const float a1 = v[((size_t)(b * SEQ + s0 + 1) * HKV + h) * DD + d];
      c[p] = (u32)f2bf(a0) | ((u32)f2bf(a1) << 16);
    }
    o.x = c[0]; o.y = c[1]; o.z = c[2]; o.w = c[3];
    *reinterpret_cast<uint4*>(vt + oo + q8 * 8) = o;
  }
}

__global__ void __launch_bounds__(256) prep_kernel(
    const float* __restrict__ q, const float* __restrict__ k,
    const float* __restrict__ v, const float* __restrict__ qw,
    const float* __restrict__ kw, u16* __restrict__ qn,
    u16* __restrict__ kn, u16* __restrict__ vt) {
  const int blk = blockIdx.x;
  const int tid = threadIdx.x;
  if (blk < 16384) {
    norm_body(q, qw, qn, 5, 0.08838834764831845f, blk, tid);
  } else if (blk < 20480) {
    norm_body(k, kw, kn, 3, 1.0f, blk - 16384, tid);
  } else {
    transv_body(v, vt, blk - 20480, tid);
  }
}

__global__ void __launch_bounds__(256) attn_kernel(
    const u16* __restrict__ qn, const u16* __restrict__ kn,
    const u16* __restrict__ vt, float* __restrict__ out) {
  __shared__ char smem[49152];
  const int tid = threadIdx.x;
  const int w = tid >> 6;
  const int lane = tid & 63;
  const int c = lane & 15;
  const int g = lane >> 4;

  // XCD-locality remap: each XCD owns 128 consecutive logical blocks.
  const int p = blockIdx.x;
  const int bid = ((p & 7) << 7) + (p >> 3);
  const int qt = bid & 63;
  const int hk = (bid >> 6) & 7;
  const int b = bid >> 9;
  const int i0 = qt * QT;
  const int h = hk * 4 + w;

  const u16* qb = qn + ((size_t)(b * HQ + h) * SEQ + i0) * DD;
  const u16* kbp = kn + (size_t)(b * HKV + hk) * SEQ * DD;
  const u16* vbp = vt + (size_t)(b * HKV + hk) * DD * SEQ;

  // Q fragments (MFMA B operand): col=c (query), k=g*8+j
  bf16x8 aq[2][4];
#pragma unroll
  for (int mt = 0; mt < 2; ++mt)
#pragma unroll
    for (int kt = 0; kt < 4; ++kt)
      aq[mt][kt] = *reinterpret_cast<const bf16x8*>(qb + (mt * 16 + c) * DD + kt * 32 + g * 8);

  int ks = i0 - WIN;
  ks = (ks < 0) ? 0 : (ks & ~63);
  const int ntl = (i0 + QT - ks + 63) >> 6;

  const float C_T = 3.70370370e-4f;       // 1/(3*CAP^2)
  const float LOG2E = 1.44269504088896f;
  const float C_E = 43.2808512266689f;    // CAP*log2(e)

  auto stageK = [&](int kb, int bufoff) {
    char* dst = smem + bufoff;
#pragma unroll
    for (int ci = 0; ci < 4; ++ci) {
      const int call = w * 4 + ci;
      const int row = call * 4 + g;
      const int ch = c ^ (row & 7);
      gl16(kbp + (size_t)(kb + row) * DD + ch * 8, dst + call * 1024);
    }
  };
  auto stageV = [&](int kb, int bufoff) {
    char* dst = smem + bufoff;
#pragma unroll
    for (int ci = 0; ci < 4; ++ci) {
      const int call = w * 4 + ci;
      const int vrow = call * 8 + (lane >> 3);
      const int vch = (lane & 7) ^ (vrow & 7);
      gl16(vbp + (size_t)vrow * SEQ + kb + vch * 8, dst + call * 1024);
    }
  };
  auto qk_tile = [&](int bufoff, f32x4 sc[2][4], int kb) {
    const char* kbuf = smem + bufoff;
    __builtin_amdgcn_s_setprio(1);
#pragma unroll
    for (int nt = 0; nt < 4; ++nt) {
      const int jb = kb + nt * 16;
      if (jb > i0 + 31 || jb + 15 < i0 - WIN) continue;  // wave-uniform skip
      const int row = nt * 16 + c;
      const int sw = row & 7;
      const char* base = kbuf + row * 256;
#pragma unroll
      for (int kt = 0; kt < 4; ++kt) {
        const bf16x8 bk = *reinterpret_cast<const bf16x8*>(base + (((kt * 4 + g) ^ sw) << 4));
        sc[0][nt] = __builtin_amdgcn_mfma_f32_16x16x32_bf16(bk, aq[0][kt], sc[0][nt], 0, 0, 0);
        sc[1][nt] = __builtin_amdgcn_mfma_f32_16x16x32_bf16(bk, aq[1][kt], sc[1][nt], 0, 0, 0);
      }
    }
    __builtin_amdgcn_s_setprio(0);
  };

  float lsum[2] = {0.0f, 0.0f};

  // ---- pass 1: 3-buffer K rotation, 1 raw barrier/iter, counted vmcnt ----
  stageK(ks, 0);
  if (ntl > 1) stageK(ks + 64, 16384);
  for (int t = 0; t < ntl; ++t) {
    const int kb = ks + t * 64;
    if (t + 1 < ntl) { WAITV4(); } else { WAITV0(); }
    SBAR();
    if (t + 2 < ntl) stageK(kb + 128, ((t + 2) % 3) * 16384);

    f32x4 sc[2][4] = {};
    qk_tile((t % 3) * 16384, sc, kb);

#pragma unroll
    for (int mt = 0; mt < 2; ++mt) {
      const int imin = i0 + mt * 16;
      const int i = imin + c;
#pragma unroll
      for (int nt = 0; nt < 4; ++nt) {
        const int jb = kb + nt * 16;
        if (jb > imin + 15 || jb + 15 < imin - WIN) continue;
        const bool needmask = (jb + 15 > imin) || (jb < imin + 15 - WIN);
        const int difg = i - jb - g * 4;   // i - j for r=0
#pragma unroll
        for (int r = 0; r < 4; ++r) {
          const float x = sc[mt][nt][r];
          const float u = fmaf(x * x * (-C_T), x, x);   // 30*tanh(x/30) cubic
          float e = __builtin_amdgcn_exp2f(fmaf(u, LOG2E, -C_E));
          if (needmask) e = ((u32)(difg - r) <= WIN) ? e : 0.0f;
          lsum[mt] += e;
        }
      }
    }
  }
  SBAR();  // protect buffers before pass-2 prologue overwrites

  float ar[2];
#pragma unroll
  for (int mt = 0; mt < 2; ++mt) {
    float l = lsum[mt];
    l += __shfl_xor(l, 16);
    l += __shfl_xor(l, 32);
    ar[mt] = 1.06f / l;
  }

  f32x4 acc[2][8] = {};

  // ---- pass 2: K single (off 0) + V double (off 16384/32768), 2 barriers/iter ----
  stageV(ks, 16384);
  stageK(ks, 0);
  WAITV0();
  SBAR();
  for (int t = 0; t < ntl; ++t) {
    const int kb = ks + t * 64;
    if (t + 1 < ntl) stageV(kb + 64, 16384 + (((t + 1) & 1) << 14));  // issue-early

    f32x4 sc[2][4] = {};
    qk_tile(0, sc, kb);
    SBAR();                                  // all waves done reading Kb
    if (t + 1 < ntl) stageK(kb + 64, 0);

    // probs -> packed bf16 pairs, in-register
    u32 pk[2][4][2];
#pragma unroll
    for (int mt = 0; mt < 2; ++mt) {
      const int imin = i0 + mt * 16;
      const int i = imin + c;
#pragma unroll
      for (int nt = 0; nt < 4; ++nt) {
        const int jb = kb + nt * 16;
        const bool inval = (jb > imin + 15) || (jb + 15 < imin - WIN);
        const bool needmask = (jb + 15 > imin) || (jb < imin + 15 - WIN);
        const int difg = i - jb - g * 4;
        float pv4[4];
#pragma unroll
        for (int r = 0; r < 4; ++r) {
          float e;
          if (inval) {
            e = 0.0f;
          } else {
            const float x = sc[mt][nt][r];
            const float u = fmaf(x * x * (-C_T), x, x);
            e = __builtin_amdgcn_exp2f(fmaf(u, LOG2E, -C_E));
            if (needmask) e = ((u32)(difg - r) <= WIN) ? e : 0.0f;
          }
          float pp = fmaf(e, ar[mt], -0.03f);
          pv4[r] = fminf(fmaxf(pp, 0.0f), 1.0f);
        }
        pk[mt][nt][0] = cvtpk(pv4[0], pv4[1]);
        pk[mt][nt][1] = cvtpk(pv4[2], pv4[3]);
      }
    }

    // exchange: build PV A-fragments via permlane swaps (no LDS).
    union PU { bf16x8 v; u32 w4[4]; };
    PU pf[2][2];
#pragma unroll
    for (int mt = 0; mt < 2; ++mt)
#pragma unroll
      for (int k2 = 0; k2 < 2; ++k2) {
        u32 x0 = pk[mt][2 * k2][0], y0 = pk[mt][2 * k2 + 1][0];
        asm("v_permlane32_swap_b32 %0, %1" : "+v"(x0), "+v"(y0));
        asm("v_permlane16_swap_b32 %0, %1" : "+v"(x0), "+v"(y0));
        u32 x1 = pk[mt][2 * k2][1], y1 = pk[mt][2 * k2 + 1][1];
        asm("v_permlane32_swap_b32 %0, %1" : "+v"(x1), "+v"(y1));
        asm("v_permlane16_swap_b32 %0, %1" : "+v"(x1), "+v"(y1));
        pf[mt][k2].w4[0] = x0;
        pf[mt][k2].w4[1] = x1;
        pf[mt][k2].w4[2] = y0;
        pf[mt][k2].w4[3] = y1;
      }

    const char* ldsV = smem + 16384 + ((t & 1) << 14);
    __builtin_amdgcn_s_setprio(1);
#pragma unroll
    for (int dt = 0; dt < 8; ++dt) {
      const int rv = dt * 16 + c;
      const int sw = rv & 7;
      const char* base = ldsV + rv * 128;
#pragma unroll
      for (int k2 = 0; k2 < 2; ++k2) {
        const bf16x8 bv = *reinterpret_cast<const bf16x8*>(base + (((k2 * 4 + g) ^ sw) << 4));
        acc[0][dt] = __builtin_amdgcn_mfma_f32_16x16x32_bf16(pf[0][k2].v, bv, acc[0][dt], 0, 0, 0);
        acc[1][dt] = __builtin_amdgcn_mfma_f32_16x16x32_bf16(pf[1][k2].v, bv, acc[1][dt], 0, 0, 0);
      }
    }
    __builtin_amdgcn_s_setprio(0);

    WAITV0();   // K(t+1)+V(t+1) landed (issued >=600cy ago, hidden)
    SBAR();
  }

  // epilogue: out[b][i][h][d] fp32; query = i0+16mt+4g+r, dim = 16dt+c
#pragma unroll
  for (int mt = 0; mt < 2; ++mt)
#pragma unroll
    for (int r = 0; r < 4; ++r) {
      const int i = i0 + mt * 16 + g * 4 + r;
      float* op = out + (((size_t)b * SEQ + i) * HQ + h) * DD + c;
#pragma unroll
      for (int dt = 0; dt < 8; ++dt) op[dt * 16] = acc[mt][dt][r];
    }
}

extern "C" void kernel_launch(void* const* d_in, const int* in_sizes, int n_in,
                              void* d_out, int out_size, void* d_ws, size_t ws_size,
                              hipStream_t stream) {
  const float* q = (const float*)d_in[0];
  const float* k = (const float*)d_in[1];
  const float* v = (const float*)d_in[2];
  const float* qw = (const float*)d_in[3];
  const float* kw = (const float*)d_in[4];
  float* out = (float*)d_out;

  u16* qn = (u16*)d_ws;                                  // [2][32][2048][128] bf16
  u16* kn = qn + (size_t)2 * HQ * SEQ * DD;              // [2][8][2048][128] bf16
  u16* vt = kn + (size_t)2 * HKV * SEQ * DD;             // [2][8][128][2048] bf16

  prep_kernel<<<20992, 256, 0, stream>>>(q, k, v, qw, kw, qn, kn, vt);
  attn_kernel<<<1024, 256, 0, stream>>>(qn, kn, vt, out);
}

// Round 6
// 129.598 us; speedup vs baseline: 1.7665x; 1.0275x over previous
//
#include <hip/hip_runtime.h>

#define SEQ 2048
#define DD 128
#define HQ 32
#define HKV 8
#define WIN 512
#define QT 32

typedef unsigned short u16;
typedef unsigned int u32;
typedef __attribute__((ext_vector_type(8))) short bf16x8;
typedef __attribute__((ext_vector_type(4))) float f32x4;

#define SBAR() asm volatile("s_barrier" ::: "memory")
#define WAITV0() asm volatile("s_waitcnt vmcnt(0)" ::: "memory")

__device__ __forceinline__ u16 f2bf(float f) {
  u32 u = __builtin_bit_cast(u32, f);
  u += 0x7FFFu + ((u >> 16) & 1u);
  return (u16)(u >> 16);
}

__device__ __forceinline__ void gl16(const void* g, void* l) {
  __builtin_amdgcn_global_load_lds(
      (const __attribute__((address_space(1))) void*)g,
      (__attribute__((address_space(3))) void*)l, 16, 0, 0);
}

__device__ __forceinline__ u32 cvtpk(float lo, float hi) {
  u32 r;
  asm("v_cvt_pk_bf16_f32 %0, %1, %2" : "=v"(r) : "v"(lo), "v"(hi));
  return r;
}

// GroupRMSNorm + weight + scale fold + bf16 + repack to [b][h][s][d]
__device__ __forceinline__ void norm_body(
    const float* __restrict__ x, const float* __restrict__ w,
    u16* __restrict__ o, int hshift, float scale, int blk, int tid) {
  const int lane = tid & 63;
  const int wv = tid >> 6;
  const int sub = lane >> 5;
  const int l5 = lane & 31;
  const int rid = blk * 8 + wv * 2 + sub;   // flattened (b,s,h)
  const int H = 1 << hshift;
  const int hh = rid & (H - 1);
  const int s = (rid >> hshift) & (SEQ - 1);
  const int b = rid >> (hshift + 11);
  const float4 xv = *(reinterpret_cast<const float4*>(x + (size_t)rid * DD) + l5);
  float ssq = xv.x * xv.x + xv.y * xv.y + xv.z * xv.z + xv.w * xv.w;
  ssq += __shfl_xor(ssq, 1);
  ssq += __shfl_xor(ssq, 2);
  ssq += __shfl_xor(ssq, 4);
  ssq += __shfl_xor(ssq, 8);
  ssq += __shfl_xor(ssq, 16);
  const float inv = rsqrtf(ssq * (1.0f / 128.0f) + 1e-5f) * scale;
  const float4 wv4 = *(reinterpret_cast<const float4*>(w + hh * DD) + l5);
  const u16 o0 = f2bf(xv.x * inv * wv4.x);
  const u16 o1 = f2bf(xv.y * inv * wv4.y);
  const u16 o2 = f2bf(xv.z * inv * wv4.z);
  const u16 o3 = f2bf(xv.w * inv * wv4.w);
  const size_t oo = (((size_t)b * H + hh) * SEQ + s) * DD + l5 * 4;
  uint2 pk;
  pk.x = (u32)o0 | ((u32)o1 << 16);
  pk.y = (u32)o2 | ((u32)o3 << 16);
  *reinterpret_cast<uint2*>(o + oo) = pk;
}

// V: fp32 [b][s][h][d] -> bf16 transposed [b][h][d][s]
__device__ __forceinline__ void transv_body(
    const float* __restrict__ v, u16* __restrict__ vt, int bid, int t) {
  const int st = bid & 31;
  const int h = (bid >> 5) & 7;
  const int b = bid >> 8;
  const int sbase = st * 64;
  const int d = t & 127;
  const int sch = (t >> 7) * 32;
  const size_t oo = (((size_t)(b * HKV + h)) * DD + d) * SEQ + sbase + sch;
#pragma unroll
  for (int q8 = 0; q8 < 4; ++q8) {
    uint4 o;
    u32 c[4];
#pragma unroll
    for (int p = 0; p < 4; ++p) {
      const int ss0 = q8 * 8 + p * 2;
      const int s0 = sbase + sch + ss0;
      const float a0 = v[((size_t)(b * SEQ + s0) * HKV + h) * DD + d];
      const float a1 = v[((size_t)(b * SEQ + s0 + 1) * HKV + h) * DD + d];
      c[p] = (u32)f2bf(a0) | ((u32)f2bf(a1) << 16);
    }
    o.x = c[0]; o.y = c[1]; o.z = c[2]; o.w = c[3];
    *reinterpret_cast<uint4*>(vt + oo + q8 * 8) = o;
  }
}

__global__ void __launch_bounds__(256) prep_kernel(
    const float* __restrict__ q, const float* __restrict__ k,
    const float* __restrict__ v, const float* __restrict__ qw,
    const float* __restrict__ kw, u16* __restrict__ qn,
    u16* __restrict__ kn, u16* __restrict__ vt) {
  const int blk = blockIdx.x;
  const int tid = threadIdx.x;
  if (blk < 16384) {
    norm_body(q, qw, qn, 5, 0.08838834764831845f, blk, tid);
  } else if (blk < 20480) {
    norm_body(k, kw, kn, 3, 1.0f, blk - 16384, tid);
  } else {
    transv_body(v, vt, blk - 20480, tid);
  }
}

__global__ void __launch_bounds__(256) attn_kernel(
    const u16* __restrict__ qn, const u16* __restrict__ kn,
    const u16* __restrict__ vt, float* __restrict__ out) {
  __shared__ char smem[32768];
  const int tid = threadIdx.x;
  const int w = tid >> 6;
  const int lane = tid & 63;
  const int c = lane & 15;
  const int g = lane >> 4;

  // XCD-locality remap: each XCD owns 128 consecutive logical blocks.
  const int p = blockIdx.x;
  const int bid = ((p & 7) << 7) + (p >> 3);
  const int qt = bid & 63;
  const int hk = (bid >> 6) & 7;
  const int b = bid >> 9;
  const int i0 = qt * QT;
  const int h = hk * 4 + w;

  const u16* qb = qn + ((size_t)(b * HQ + h) * SEQ + i0) * DD;
  const u16* kbp = kn + (size_t)(b * HKV + hk) * SEQ * DD;
  const u16* vbp = vt + (size_t)(b * HKV + hk) * DD * SEQ;

  // Q fragments (MFMA B operand): col=c (query), k=g*8+j
  bf16x8 aq[2][4];
#pragma unroll
  for (int mt = 0; mt < 2; ++mt)
#pragma unroll
    for (int kt = 0; kt < 4; ++kt)
      aq[mt][kt] = *reinterpret_cast<const bf16x8*>(qb + (mt * 16 + c) * DD + kt * 32 + g * 8);

  int ks = i0 - WIN;
  ks = (ks < 0) ? 0 : (ks & ~63);
  const int ntl = (i0 + QT - ks + 63) >> 6;       // 64-key tiles, pass 1
  const int ks2 = (i0 - WIN < 0) ? 0 : (i0 - WIN); // 32-aligned already
  const int ntl2 = (i0 + QT - ks2) >> 5;          // 32-key tiles, pass 2

  const float C_T = 3.70370370e-4f;       // 1/(3*CAP^2)
  const float LOG2E = 1.44269504088896f;
  const float C_E = 43.2808512266689f;    // CAP*log2(e)

  // -------- staging helpers (XOR-swizzled global source, linear LDS dest) ----
  auto stageK = [&](int kb, int bufoff) {   // 64 keys x 256B = 16KB
    char* dst = smem + bufoff;
#pragma unroll
    for (int ci = 0; ci < 4; ++ci) {
      const int call = w * 4 + ci;
      const int row = call * 4 + g;
      const int ch = c ^ (row & 7);
      gl16(kbp + (size_t)(kb + row) * DD + ch * 8, dst + call * 1024);
    }
  };
  auto stageK2 = [&](int kb, int bufoff) {  // 32 keys x 256B = 8KB
    char* dst = smem + bufoff;
#pragma unroll
    for (int ci = 0; ci < 2; ++ci) {
      const int call = w * 2 + ci;
      const int row = call * 4 + g;
      const int ch = c ^ (row & 7);
      gl16(kbp + (size_t)(kb + row) * DD + ch * 8, dst + call * 1024);
    }
  };
  auto stageV2 = [&](int kb, int bufoff) {  // 128 dims x 64B = 8KB
    char* dst = smem + bufoff;
#pragma unroll
    for (int ci = 0; ci < 2; ++ci) {
      const int call = w * 2 + ci;
      const int vrow = call * 16 + (lane >> 2);
      const int vch = (lane & 3) ^ (vrow & 3);
      gl16(vbp + (size_t)vrow * SEQ + kb + vch * 8, dst + call * 1024);
    }
  };
  auto qk_tile = [&](int bufoff, f32x4 sc[2][4], int kb) {  // 64-key QK
    const char* kbuf = smem + bufoff;
    __builtin_amdgcn_s_setprio(1);
#pragma unroll
    for (int nt = 0; nt < 4; ++nt) {
      const int jb = kb + nt * 16;
      if (jb > i0 + 31 || jb + 15 < i0 - WIN) continue;  // wave-uniform skip
      const int row = nt * 16 + c;
      const int sw = row & 7;
      const char* base = kbuf + row * 256;
#pragma unroll
      for (int kt = 0; kt < 4; ++kt) {
        const bf16x8 bk = *reinterpret_cast<const bf16x8*>(base + (((kt * 4 + g) ^ sw) << 4));
        sc[0][nt] = __builtin_amdgcn_mfma_f32_16x16x32_bf16(bk, aq[0][kt], sc[0][nt], 0, 0, 0);
        sc[1][nt] = __builtin_amdgcn_mfma_f32_16x16x32_bf16(bk, aq[1][kt], sc[1][nt], 0, 0, 0);
      }
    }
    __builtin_amdgcn_s_setprio(0);
  };

  float lsum[2] = {0.0f, 0.0f};

  // ---- pass 1: 64-key tiles, K 2x16KB double buffer, 1 barrier/iter ----
  stageK(ks, 0);
  for (int t = 0; t < ntl; ++t) {
    const int kb = ks + t * 64;
    WAITV0();
    SBAR();
    if (t + 1 < ntl) stageK(kb + 64, ((t + 1) & 1) << 14);

    f32x4 sc[2][4] = {};
    qk_tile((t & 1) << 14, sc, kb);

#pragma unroll
    for (int mt = 0; mt < 2; ++mt) {
      const int imin = i0 + mt * 16;
      const int i = imin + c;
#pragma unroll
      for (int nt = 0; nt < 4; ++nt) {
        const int jb = kb + nt * 16;
        if (jb > imin + 15 || jb + 15 < imin - WIN) continue;
        const bool needmask = (jb + 15 > imin) || (jb < imin + 15 - WIN);
        const int difg = i - jb - g * 4;   // i - j for r=0
#pragma unroll
        for (int r = 0; r < 4; ++r) {
          const float x = sc[mt][nt][r];
          const float u = fmaf(x * x * (-C_T), x, x);   // 30*tanh(x/30) cubic
          float e = __builtin_amdgcn_exp2f(fmaf(u, LOG2E, -C_E));
          if (needmask) e = ((u32)(difg - r) <= WIN) ? e : 0.0f;
          lsum[mt] += e;
        }
      }
    }
  }
  WAITV0();
  SBAR();  // protect buffers before pass-2 prologue overwrites

  // pass-2 prologue staging first, reduction hides under it
  stageK2(ks2, 0);
  stageV2(ks2, 16384);

  float ar[2];
#pragma unroll
  for (int mt = 0; mt < 2; ++mt) {
    float l = lsum[mt];
    l += __shfl_xor(l, 16);
    l += __shfl_xor(l, 32);
    ar[mt] = 1.06f / l;
  }

  f32x4 acc[2][8] = {};

  // ---- pass 2: 32-key tiles, K 2x8KB + V 2x8KB double buffers, 1 barrier/iter ----
  for (int t = 0; t < ntl2; ++t) {
    const int kb = ks2 + t * 32;
    WAITV0();
    SBAR();
    if (t + 1 < ntl2) {
      stageK2(kb + 32, ((t + 1) & 1) << 13);
      stageV2(kb + 32, 16384 + (((t + 1) & 1) << 13));
    }
    const char* ldsK = smem + ((t & 1) << 13);
    const char* ldsV = smem + 16384 + ((t & 1) << 13);

    f32x4 sc[2][2] = {};
    __builtin_amdgcn_s_setprio(1);
#pragma unroll
    for (int nt = 0; nt < 2; ++nt) {
      const int row = nt * 16 + c;
      const int sw = row & 7;
      const char* base = ldsK + row * 256;
#pragma unroll
      for (int kt = 0; kt < 4; ++kt) {
        const bf16x8 bk = *reinterpret_cast<const bf16x8*>(base + (((kt * 4 + g) ^ sw) << 4));
        sc[0][nt] = __builtin_amdgcn_mfma_f32_16x16x32_bf16(bk, aq[0][kt], sc[0][nt], 0, 0, 0);
        sc[1][nt] = __builtin_amdgcn_mfma_f32_16x16x32_bf16(bk, aq[1][kt], sc[1][nt], 0, 0, 0);
      }
    }
    __builtin_amdgcn_s_setprio(0);

    // probs -> packed bf16 pairs, in-register
    u32 pk[2][2][2];
#pragma unroll
    for (int mt = 0; mt < 2; ++mt) {
      const int imin = i0 + mt * 16;
      const int i = imin + c;
#pragma unroll
      for (int nt = 0; nt < 2; ++nt) {
        const int jb = kb + nt * 16;
        const bool inval = (jb > imin + 15) || (jb + 15 < imin - WIN);
        const bool needmask = (jb + 15 > imin) || (jb < imin + 15 - WIN);
        const int difg = i - jb - g * 4;
        float pv4[4];
#pragma unroll
        for (int r = 0; r < 4; ++r) {
          float e;
          if (inval) {
            e = 0.0f;
          } else {
            const float x = sc[mt][nt][r];
            const float u = fmaf(x * x * (-C_T), x, x);
            e = __builtin_amdgcn_exp2f(fmaf(u, LOG2E, -C_E));
            if (needmask) e = ((u32)(difg - r) <= WIN) ? e : 0.0f;
          }
          float pp = fmaf(e, ar[mt], -0.03f);
          pv4[r] = fminf(fmaxf(pp, 0.0f), 1.0f);
        }
        pk[mt][nt][0] = cvtpk(pv4[0], pv4[1]);
        pk[mt][nt][1] = cvtpk(pv4[2], pv4[3]);
      }
    }

    // exchange: build PV A-fragments via permlane swaps (no LDS).
    union PU { bf16x8 v; u32 w4[4]; };
    PU pf[2];
#pragma unroll
    for (int mt = 0; mt < 2; ++mt) {
      u32 x0 = pk[mt][0][0], y0 = pk[mt][1][0];
      asm("v_permlane32_swap_b32 %0, %1" : "+v"(x0), "+v"(y0));
      asm("v_permlane16_swap_b32 %0, %1" : "+v"(x0), "+v"(y0));
      u32 x1 = pk[mt][0][1], y1 = pk[mt][1][1];
      asm("v_permlane32_swap_b32 %0, %1" : "+v"(x1), "+v"(y1));
      asm("v_permlane16_swap_b32 %0, %1" : "+v"(x1), "+v"(y1));
      pf[mt].w4[0] = x0;
      pf[mt].w4[1] = x1;
      pf[mt].w4[2] = y0;
      pf[mt].w4[3] = y1;
    }

    __builtin_amdgcn_s_setprio(1);
#pragma unroll
    for (int dt = 0; dt < 8; ++dt) {
      const int rv = dt * 16 + c;
      const bf16x8 bv = *reinterpret_cast<const bf16x8*>(
          ldsV + rv * 64 + (((g ^ (rv & 3))) << 4));
      acc[0][dt] = __builtin_amdgcn_mfma_f32_16x16x32_bf16(pf[0].v, bv, acc[0][dt], 0, 0, 0);
      acc[1][dt] = __builtin_amdgcn_mfma_f32_16x16x32_bf16(pf[1].v, bv, acc[1][dt], 0, 0, 0);
    }
    __builtin_amdgcn_s_setprio(0);
  }

  // epilogue: out[b][i][h][d] fp32; query = i0+16mt+4g+r, dim = 16dt+c
#pragma unroll
  for (int mt = 0; mt < 2; ++mt)
#pragma unroll
    for (int r = 0; r < 4; ++r) {
      const int i = i0 + mt * 16 + g * 4 + r;
      float* op = out + (((size_t)b * SEQ + i) * HQ + h) * DD + c;
#pragma unroll
      for (int dt = 0; dt < 8; ++dt) op[dt * 16] = acc[mt][dt][r];
    }
}

extern "C" void kernel_launch(void* const* d_in, const int* in_sizes, int n_in,
                              void* d_out, int out_size, void* d_ws, size_t ws_size,
                              hipStream_t stream) {
  const float* q = (const float*)d_in[0];
  const float* k = (const float*)d_in[1];
  const float* v = (const float*)d_in[2];
  const float* qw = (const float*)d_in[3];
  const float* kw = (const float*)d_in[4];
  float* out = (float*)d_out;

  u16* qn = (u16*)d_ws;                                  // [2][32][2048][128] bf16
  u16* kn = qn + (size_t)2 * HQ * SEQ * DD;              // [2][8][2048][128] bf16
  u16* vt = kn + (size_t)2 * HKV * SEQ * DD;             // [2][8][128][2048] bf16

  prep_kernel<<<20992, 256, 0, stream>>>(q, k, v, qw, kw, qn, kn, vt);
  attn_kernel<<<1024, 256, 0, stream>>>(qn, kn, vt, out);
}

// Round 7
// 122.681 us; speedup vs baseline: 1.8661x; 1.0564x over previous
//
#include <hip/hip_runtime.h>

#define SEQ 2048
#define DD 128
#define HQ 32
#define HKV 8
#define WIN 512

typedef unsigned short u16;
typedef unsigned int u32;
typedef __attribute__((ext_vector_type(8))) short bf16x8;
typedef __attribute__((ext_vector_type(4))) float f32x4;
typedef __attribute__((ext_vector_type(2))) float f32x2;

#define SBAR() asm volatile("s_barrier" ::: "memory")
#define WAITV0() asm volatile("s_waitcnt vmcnt(0)" ::: "memory")

__device__ __forceinline__ u16 f2bf(float f) {
  u32 u = __builtin_bit_cast(u32, f);
  u += 0x7FFFu + ((u >> 16) & 1u);
  return (u16)(u >> 16);
}

__device__ __forceinline__ void gl16(const void* g, void* l) {
  __builtin_amdgcn_global_load_lds(
      (const __attribute__((address_space(1))) void*)g,
      (__attribute__((address_space(3))) void*)l, 16, 0, 0);
}

__device__ __forceinline__ u32 cvtpk(float lo, float hi) {
  u32 r;
  asm("v_cvt_pk_bf16_f32 %0, %1, %2" : "=v"(r) : "v"(lo), "v"(hi));
  return r;
}

__device__ __forceinline__ f32x2 pk_mul(f32x2 a, f32x2 b) {
  f32x2 d;
  asm("v_pk_mul_f32 %0, %1, %2" : "=v"(d) : "v"(a), "v"(b));
  return d;
}
__device__ __forceinline__ f32x2 pk_fma(f32x2 a, f32x2 b, f32x2 c) {
  f32x2 d;
  asm("v_pk_fma_f32 %0, %1, %2, %3" : "=v"(d) : "v"(a), "v"(b), "v"(c));
  return d;
}

// exp2 argument for capped score pair: x*log2e - C_E - (C_T*log2e)*x^3
__device__ __forceinline__ f32x2 score2(f32x2 x, f32x2 vL2E, f32x2 vmCE, f32x2 vmCTL) {
  f32x2 x2 = pk_mul(x, x);
  f32x2 a1 = pk_fma(x, vL2E, vmCE);
  f32x2 b1 = pk_mul(x2, vmCTL);
  return pk_fma(b1, x, a1);
}

// GroupRMSNorm + weight + scale fold + bf16 + repack to [b][h][s][d]
__device__ __forceinline__ void norm_body(
    const float* __restrict__ x, const float* __restrict__ w,
    u16* __restrict__ o, int hshift, float scale, int blk, int tid) {
  const int lane = tid & 63;
  const int wv = tid >> 6;
  const int sub = lane >> 5;
  const int l5 = lane & 31;
  const int rid = blk * 8 + wv * 2 + sub;   // flattened (b,s,h)
  const int H = 1 << hshift;
  const int hh = rid & (H - 1);
  const int s = (rid >> hshift) & (SEQ - 1);
  const int b = rid >> (hshift + 11);
  const float4 xv = *(reinterpret_cast<const float4*>(x + (size_t)rid * DD) + l5);
  float ssq = xv.x * xv.x + xv.y * xv.y + xv.z * xv.z + xv.w * xv.w;
  ssq += __shfl_xor(ssq, 1);
  ssq += __shfl_xor(ssq, 2);
  ssq += __shfl_xor(ssq, 4);
  ssq += __shfl_xor(ssq, 8);
  ssq += __shfl_xor(ssq, 16);
  const float inv = rsqrtf(ssq * (1.0f / 128.0f) + 1e-5f) * scale;
  const float4 wv4 = *(reinterpret_cast<const float4*>(w + hh * DD) + l5);
  const u16 o0 = f2bf(xv.x * inv * wv4.x);
  const u16 o1 = f2bf(xv.y * inv * wv4.y);
  const u16 o2 = f2bf(xv.z * inv * wv4.z);
  const u16 o3 = f2bf(xv.w * inv * wv4.w);
  const size_t oo = (((size_t)b * H + hh) * SEQ + s) * DD + l5 * 4;
  uint2 pk;
  pk.x = (u32)o0 | ((u32)o1 << 16);
  pk.y = (u32)o2 | ((u32)o3 << 16);
  *reinterpret_cast<uint2*>(o + oo) = pk;
}

// V: fp32 [b][s][h][d] -> bf16 transposed [b][h][d][s]
__device__ __forceinline__ void transv_body(
    const float* __restrict__ v, u16* __restrict__ vt, int bid, int t) {
  const int st = bid & 31;
  const int h = (bid >> 5) & 7;
  const int b = bid >> 8;
  const int sbase = st * 64;
  const int d = t & 127;
  const int sch = (t >> 7) * 32;
  const size_t oo = (((size_t)(b * HKV + h)) * DD + d) * SEQ + sbase + sch;
#pragma unroll
  for (int q8 = 0; q8 < 4; ++q8) {
    uint4 o;
    u32 c[4];
#pragma unroll
    for (int p = 0; p < 4; ++p) {
      const int ss0 = q8 * 8 + p * 2;
      const int s0 = sbase + sch + ss0;
      const float a0 = v[((size_t)(b * SEQ + s0) * HKV + h) * DD + d];
      const float a1 = v[((size_t)(b * SEQ + s0 + 1) * HKV + h) * DD + d];
      c[p] = (u32)f2bf(a0) | ((u32)f2bf(a1) << 16);
    }
    o.x = c[0]; o.y = c[1]; o.z = c[2]; o.w = c[3];
    *reinterpret_cast<uint4*>(vt + oo + q8 * 8) = o;
  }
}

__global__ void __launch_bounds__(256) prep_kernel(
    const float* __restrict__ q, const float* __restrict__ k,
    const float* __restrict__ v, const float* __restrict__ qw,
    const float* __restrict__ kw, u16* __restrict__ qn,
    u16* __restrict__ kn, u16* __restrict__ vt) {
  const int blk = blockIdx.x;
  const int tid = threadIdx.x;
  if (blk < 16384) {
    norm_body(q, qw, qn, 5, 0.08838834764831845f, blk, tid);
  } else if (blk < 20480) {
    norm_body(k, kw, kn, 3, 1.0f, blk - 16384, tid);
  } else {
    transv_body(v, vt, blk - 20480, tid);
  }
}

__global__ void __launch_bounds__(256) attn_kernel(
    const u16* __restrict__ qn, const u16* __restrict__ kn,
    const u16* __restrict__ vt, float* __restrict__ out) {
  __shared__ char smem[32768];
  const int tid = threadIdx.x;
  const int w = tid >> 6;
  const int lane = tid & 63;
  const int c = lane & 15;
  const int g = lane >> 4;

  // 2048 blocks; XCD-locality remap: each XCD owns 256 consecutive logical
  // blocks = 2 (b,hk) strips. qt reversed so heaviest blocks dispatch first.
  const int p = blockIdx.x;
  const int bid = ((p & 7) << 8) + (p >> 3);
  const int qt = (bid & 127) ^ 127;
  const int hk = (bid >> 7) & 7;
  const int b = bid >> 10;
  const int i0 = qt * 16;
  const int h = hk * 4 + w;

  const u16* qb = qn + ((size_t)(b * HQ + h) * SEQ + i0) * DD;
  const u16* kbp = kn + (size_t)(b * HKV + hk) * SEQ * DD;
  const u16* vbp = vt + (size_t)(b * HKV + hk) * DD * SEQ;

  // Q fragments (MFMA B operand): col=c (query), k=g*8+j
  bf16x8 aq[4];
#pragma unroll
  for (int kt = 0; kt < 4; ++kt)
    aq[kt] = *reinterpret_cast<const bf16x8*>(qb + c * DD + kt * 32 + g * 8);

  int ks = i0 - WIN;
  ks = (ks < 0) ? 0 : (ks & ~63);
  const int ntl = (i0 + 16 - ks + 63) >> 6;          // 64-key tiles, pass 1
  const int ks2 = (i0 - WIN < 0) ? 0 : (i0 - WIN);   // multiple of 16
  const int ntl2 = (i0 + 16 - ks2 + 31) >> 5;        // 32-key tiles, pass 2

  const f32x2 vL2E = {1.44269504088896f, 1.44269504088896f};
  const f32x2 vmCE = {-43.2808512266689f, -43.2808512266689f};   // -CAP*log2e
  const f32x2 vmCTL = {-5.343315e-4f, -5.343315e-4f};            // -log2e/(3*CAP^2)

  // -------- staging (XOR-swizzled global source, linear LDS dest) ----
  auto stageK = [&](int kb, int bufoff) {   // 64 keys x 256B = 16KB
    char* dst = smem + bufoff;
#pragma unroll
    for (int ci = 0; ci < 4; ++ci) {
      const int call = w * 4 + ci;
      const int row = call * 4 + g;
      const int ch = c ^ (row & 7);
      gl16(kbp + (size_t)(kb + row) * DD + ch * 8, dst + call * 1024);
    }
  };
  auto stageK2 = [&](int kb, int bufoff) {  // 32 keys x 256B = 8KB
    char* dst = smem + bufoff;
#pragma unroll
    for (int ci = 0; ci < 2; ++ci) {
      const int call = w * 2 + ci;
      const int row = call * 4 + g;
      const int ch = c ^ (row & 7);
      gl16(kbp + (size_t)(kb + row) * DD + ch * 8, dst + call * 1024);
    }
  };
  // V tile: [64 rows][128B], row r = dims {2r, 2r+1} x 32 keys, 8-chunk XOR
  auto stageV2 = [&](int kb, int bufoff) {  // 8KB
    char* dst = smem + bufoff;
#pragma unroll
    for (int ci = 0; ci < 2; ++ci) {
      const int call = w * 2 + ci;
      const int row = call * 8 + (lane >> 3);
      const int col = (lane & 7) ^ (row & 7);
      const int d = row * 2 + (col >> 2);
      const int kc = col & 3;
      gl16(vbp + (size_t)d * SEQ + kb + kc * 8, dst + call * 1024);
    }
  };

  float lsum = 0.0f;

  // ---- pass 1: 64-key tiles, K 2x16KB double buffer, 1 barrier/iter ----
  stageK(ks, 0);
  for (int t = 0; t < ntl; ++t) {
    const int kb = ks + t * 64;
    WAITV0();
    SBAR();
    if (t + 1 < ntl) stageK(kb + 64, ((t + 1) & 1) << 14);

    const char* kbuf = smem + ((t & 1) << 14);
    f32x4 sc[4] = {};
    __builtin_amdgcn_s_setprio(1);
#pragma unroll
    for (int nt = 0; nt < 4; ++nt) {
      const int jb = kb + nt * 16;
      if (jb > i0 + 15 || jb + 15 < i0 - WIN) continue;  // wave-uniform skip
      const int row = nt * 16 + c;
      const int sw = row & 7;
      const char* base = kbuf + row * 256;
#pragma unroll
      for (int kt = 0; kt < 4; ++kt) {
        const bf16x8 bk = *reinterpret_cast<const bf16x8*>(base + (((kt * 4 + g) ^ sw) << 4));
        sc[nt] = __builtin_amdgcn_mfma_f32_16x16x32_bf16(bk, aq[kt], sc[nt], 0, 0, 0);
      }
    }
    __builtin_amdgcn_s_setprio(0);

#pragma unroll
    for (int nt = 0; nt < 4; ++nt) {
      const int jb = kb + nt * 16;
      if (jb > i0 + 15 || jb + 15 < i0 - WIN) continue;
      const bool needmask = (jb + 15 > i0) || (jb < i0 + 15 - WIN);
      f32x2 lo = __builtin_shufflevector(sc[nt], sc[nt], 0, 1);
      f32x2 hi = __builtin_shufflevector(sc[nt], sc[nt], 2, 3);
      const f32x2 a0 = score2(lo, vL2E, vmCE, vmCTL);
      const f32x2 a1 = score2(hi, vL2E, vmCE, vmCTL);
      float e0 = __builtin_amdgcn_exp2f(a0[0]);
      float e1 = __builtin_amdgcn_exp2f(a0[1]);
      float e2 = __builtin_amdgcn_exp2f(a1[0]);
      float e3 = __builtin_amdgcn_exp2f(a1[1]);
      if (needmask) {
        const int difg = i0 + c - jb - g * 4;   // i - j for r=0
        e0 = ((u32)(difg - 0) <= WIN) ? e0 : 0.0f;
        e1 = ((u32)(difg - 1) <= WIN) ? e1 : 0.0f;
        e2 = ((u32)(difg - 2) <= WIN) ? e2 : 0.0f;
        e3 = ((u32)(difg - 3) <= WIN) ? e3 : 0.0f;
      }
      lsum += (e0 + e1) + (e2 + e3);
    }
  }
  WAITV0();
  SBAR();  // all waves done with pass-1 buffers

  // pass-2 prologue staging first; reduction hides under it
  stageK2(ks2, 0);
  stageV2(ks2, 16384);

  float l = lsum;
  l += __shfl_xor(l, 16);
  l += __shfl_xor(l, 32);
  const float ar = 1.06f / l;
  const f32x2 var2 = {ar, ar};
  const f32x2 vm003 = {-0.03f, -0.03f};

  f32x4 acc[8] = {};

  // ---- pass 2: 32-key tiles, K 2x8KB + V 2x8KB double buffers ----
  for (int t = 0; t < ntl2; ++t) {
    const int kb = ks2 + t * 32;
    WAITV0();
    SBAR();
    if (t + 1 < ntl2) {
      stageK2(kb + 32, ((t + 1) & 1) << 13);
      stageV2(kb + 32, 16384 + (((t + 1) & 1) << 13));
    }
    const char* ldsK = smem + ((t & 1) << 13);
    const char* ldsV = smem + 16384 + ((t & 1) << 13);

    f32x4 sc[2] = {};
    __builtin_amdgcn_s_setprio(1);
#pragma unroll
    for (int nt = 0; nt < 2; ++nt) {
      const int row = nt * 16 + c;
      const int sw = row & 7;
      const char* base = ldsK + row * 256;
#pragma unroll
      for (int kt = 0; kt < 4; ++kt) {
        const bf16x8 bk = *reinterpret_cast<const bf16x8*>(base + (((kt * 4 + g) ^ sw) << 4));
        sc[nt] = __builtin_amdgcn_mfma_f32_16x16x32_bf16(bk, aq[kt], sc[nt], 0, 0, 0);
      }
    }
    __builtin_amdgcn_s_setprio(0);

    // probs -> packed bf16 pairs, in-register
    u32 pkv[2][2];
#pragma unroll
    for (int nt = 0; nt < 2; ++nt) {
      const int jb = kb + nt * 16;
      const bool inval = (jb > i0 + 15) || (jb + 15 < i0 - WIN);
      const bool needmask = (jb + 15 > i0) || (jb < i0 + 15 - WIN);
      float e0, e1, e2, e3;
      if (inval) {
        e0 = e1 = e2 = e3 = 0.0f;
      } else {
        f32x2 lo = __builtin_shufflevector(sc[nt], sc[nt], 0, 1);
        f32x2 hi = __builtin_shufflevector(sc[nt], sc[nt], 2, 3);
        const f32x2 a0 = score2(lo, vL2E, vmCE, vmCTL);
        const f32x2 a1 = score2(hi, vL2E, vmCE, vmCTL);
        e0 = __builtin_amdgcn_exp2f(a0[0]);
        e1 = __builtin_amdgcn_exp2f(a0[1]);
        e2 = __builtin_amdgcn_exp2f(a1[0]);
        e3 = __builtin_amdgcn_exp2f(a1[1]);
        if (needmask) {
          const int difg = i0 + c - jb - g * 4;
          e0 = ((u32)(difg - 0) <= WIN) ? e0 : 0.0f;
          e1 = ((u32)(difg - 1) <= WIN) ? e1 : 0.0f;
          e2 = ((u32)(difg - 2) <= WIN) ? e2 : 0.0f;
          e3 = ((u32)(difg - 3) <= WIN) ? e3 : 0.0f;
        }
      }
      const f32x2 eA = {e0, e1};
      const f32x2 eB = {e2, e3};
      const f32x2 pA = pk_fma(eA, var2, vm003);
      const f32x2 pB = pk_fma(eB, var2, vm003);
      const float p0 = __builtin_amdgcn_fmed3f(pA[0], 0.0f, 1.0f);
      const float p1 = __builtin_amdgcn_fmed3f(pA[1], 0.0f, 1.0f);
      const float p2 = __builtin_amdgcn_fmed3f(pB[0], 0.0f, 1.0f);
      const float p3 = __builtin_amdgcn_fmed3f(pB[1], 0.0f, 1.0f);
      pkv[nt][0] = cvtpk(p0, p1);
      pkv[nt][1] = cvtpk(p2, p3);
    }

    // exchange: build PV A-fragment via permlane swaps (no LDS)
    union PU { bf16x8 v; u32 w4[4]; };
    PU pf;
    {
      u32 x0 = pkv[0][0], y0 = pkv[1][0];
      asm("v_permlane32_swap_b32 %0, %1" : "+v"(x0), "+v"(y0));
      asm("v_permlane16_swap_b32 %0, %1" : "+v"(x0), "+v"(y0));
      u32 x1 = pkv[0][1], y1 = pkv[1][1];
      asm("v_permlane32_swap_b32 %0, %1" : "+v"(x1), "+v"(y1));
      asm("v_permlane16_swap_b32 %0, %1" : "+v"(x1), "+v"(y1));
      pf.w4[0] = x0;
      pf.w4[1] = x1;
      pf.w4[2] = y0;
      pf.w4[3] = y1;
    }

    __builtin_amdgcn_s_setprio(1);
#pragma unroll
    for (int dt = 0; dt < 8; ++dt) {
      const int rowv = dt * 8 + (c >> 1);
      const int colv = (c & 1) * 4 + g;
      const bf16x8 bv = *reinterpret_cast<const bf16x8*>(
          ldsV + rowv * 128 + ((colv ^ (rowv & 7)) << 4));
      acc[dt] = __builtin_amdgcn_mfma_f32_16x16x32_bf16(pf.v, bv, acc[dt], 0, 0, 0);
    }
    __builtin_amdgcn_s_setprio(0);
  }

  // epilogue: out[b][i][h][d] fp32; query = i0+4g+r, dim = 16dt+c
#pragma unroll
  for (int r = 0; r < 4; ++r) {
    const int i = i0 + g * 4 + r;
    float* op = out + (((size_t)b * SEQ + i) * HQ + h) * DD + c;
#pragma unroll
    for (int dt = 0; dt < 8; ++dt) op[dt * 16] = acc[dt][r];
  }
}

extern "C" void kernel_launch(void* const* d_in, const int* in_sizes, int n_in,
                              void* d_out, int out_size, void* d_ws, size_t ws_size,
                              hipStream_t stream) {
  const float* q = (const float*)d_in[0];
  const float* k = (const float*)d_in[1];
  const float* v = (const float*)d_in[2];
  const float* qw = (const float*)d_in[3];
  const float* kw = (const float*)d_in[4];
  float* out = (float*)d_out;

  u16* qn = (u16*)d_ws;                                  // [2][32][2048][128] bf16
  u16* kn = qn + (size_t)2 * HQ * SEQ * DD;              // [2][8][2048][128] bf16
  u16* vt = kn + (size_t)2 * HKV * SEQ * DD;             // [2][8][128][2048] bf16

  prep_kernel<<<20992, 256, 0, stream>>>(q, k, v, qw, kw, qn, kn, vt);
  attn_kernel<<<2048, 256, 0, stream>>>(qn, kn, vt, out);
}

// Round 8
// 93.548 us; speedup vs baseline: 2.4473x; 1.3114x over previous
//
#include <hip/hip_runtime.h>

#define SEQ 2048
#define DD 128
#define HQ 32
#define HKV 8
#define WIN 512

typedef unsigned short u16;
typedef unsigned int u32;
typedef __attribute__((ext_vector_type(8))) short bf16x8;
typedef __attribute__((ext_vector_type(4))) float f32x4;
typedef __attribute__((ext_vector_type(2))) float f32x2;

#define SBAR() asm volatile("s_barrier" ::: "memory")
#define WAITV0() asm volatile("s_waitcnt vmcnt(0)" ::: "memory")

__device__ __forceinline__ u16 f2bf(float f) {
  u32 u = __builtin_bit_cast(u32, f);
  u += 0x7FFFu + ((u >> 16) & 1u);
  return (u16)(u >> 16);
}

__device__ __forceinline__ void gl16(const void* g, void* l) {
  __builtin_amdgcn_global_load_lds(
      (const __attribute__((address_space(1))) void*)g,
      (__attribute__((address_space(3))) void*)l, 16, 0, 0);
}

__device__ __forceinline__ u32 cvtpk(float lo, float hi) {
  u32 r;
  asm("v_cvt_pk_bf16_f32 %0, %1, %2" : "=v"(r) : "v"(lo), "v"(hi));
  return r;
}

__device__ __forceinline__ f32x2 pk_mul(f32x2 a, f32x2 b) {
  f32x2 d;
  asm("v_pk_mul_f32 %0, %1, %2" : "=v"(d) : "v"(a), "v"(b));
  return d;
}
__device__ __forceinline__ f32x2 pk_fma(f32x2 a, f32x2 b, f32x2 c) {
  f32x2 d;
  asm("v_pk_fma_f32 %0, %1, %2, %3" : "=v"(d) : "v"(a), "v"(b), "v"(c));
  return d;
}
__device__ __forceinline__ f32x2 pk_add(f32x2 a, f32x2 b) {
  f32x2 d;
  asm("v_pk_add_f32 %0, %1, %2" : "=v"(d) : "v"(a), "v"(b));
  return d;
}

// exp2 argument for capped score pair: x*log2e - C_E - (C_T*log2e)*x^3
__device__ __forceinline__ f32x2 score2(f32x2 x, f32x2 vL2E, f32x2 vmCE, f32x2 vmCTL) {
  f32x2 x2 = pk_mul(x, x);
  f32x2 a1 = pk_fma(x, vL2E, vmCE);
  f32x2 b1 = pk_mul(x2, vmCTL);
  return pk_fma(b1, x, a1);
}

// unpack 2 bf16 (packed u32) -> f32x2
__device__ __forceinline__ f32x2 unpk(u32 wv) {
  f32x2 r;
  r[0] = __builtin_bit_cast(float, wv << 16);
  r[1] = __builtin_bit_cast(float, wv & 0xFFFF0000u);
  return r;
}

// GroupRMSNorm + weight + scale fold + bf16 + repack to [b][h][s][d]
__device__ __forceinline__ void norm_body(
    const float* __restrict__ x, const float* __restrict__ w,
    u16* __restrict__ o, int hshift, float scale, int blk, int tid) {
  const int lane = tid & 63;
  const int wv = tid >> 6;
  const int sub = lane >> 5;
  const int l5 = lane & 31;
  const int rid = blk * 8 + wv * 2 + sub;   // flattened (b,s,h)
  const int H = 1 << hshift;
  const int hh = rid & (H - 1);
  const int s = (rid >> hshift) & (SEQ - 1);
  const int b = rid >> (hshift + 11);
  const float4 xv = *(reinterpret_cast<const float4*>(x + (size_t)rid * DD) + l5);
  float ssq = xv.x * xv.x + xv.y * xv.y + xv.z * xv.z + xv.w * xv.w;
  ssq += __shfl_xor(ssq, 1);
  ssq += __shfl_xor(ssq, 2);
  ssq += __shfl_xor(ssq, 4);
  ssq += __shfl_xor(ssq, 8);
  ssq += __shfl_xor(ssq, 16);
  const float inv = rsqrtf(ssq * (1.0f / 128.0f) + 1e-5f) * scale;
  const float4 wv4 = *(reinterpret_cast<const float4*>(w + hh * DD) + l5);
  const u16 o0 = f2bf(xv.x * inv * wv4.x);
  const u16 o1 = f2bf(xv.y * inv * wv4.y);
  const u16 o2 = f2bf(xv.z * inv * wv4.z);
  const u16 o3 = f2bf(xv.w * inv * wv4.w);
  const size_t oo = (((size_t)b * H + hh) * SEQ + s) * DD + l5 * 4;
  uint2 pk;
  pk.x = (u32)o0 | ((u32)o1 << 16);
  pk.y = (u32)o2 | ((u32)o3 << 16);
  *reinterpret_cast<uint2*>(o + oo) = pk;
}

// V: fp32 [b][s][h][d] -> bf16 transposed [b][h][d][s]
__device__ __forceinline__ void transv_body(
    const float* __restrict__ v, u16* __restrict__ vt, int bid, int t) {
  const int st = bid & 31;
  const int h = (bid >> 5) & 7;
  const int b = bid >> 8;
  const int sbase = st * 64;
  const int d = t & 127;
  const int sch = (t >> 7) * 32;
  const size_t oo = (((size_t)(b * HKV + h)) * DD + d) * SEQ + sbase + sch;
#pragma unroll
  for (int q8 = 0; q8 < 4; ++q8) {
    uint4 o;
    u32 c[4];
#pragma unroll
    for (int p = 0; p < 4; ++p) {
      const int ss0 = q8 * 8 + p * 2;
      const int s0 = sbase + sch + ss0;
      const float a0 = v[((size_t)(b * SEQ + s0) * HKV + h) * DD + d];
      const float a1 = v[((size_t)(b * SEQ + s0 + 1) * HKV + h) * DD + d];
      c[p] = (u32)f2bf(a0) | ((u32)f2bf(a1) << 16);
    }
    o.x = c[0]; o.y = c[1]; o.z = c[2]; o.w = c[3];
    *reinterpret_cast<uint4*>(vt + oo + q8 * 8) = o;
  }
}

__global__ void __launch_bounds__(256) prep_kernel(
    const float* __restrict__ q, const float* __restrict__ k,
    const float* __restrict__ v, const float* __restrict__ qw,
    const float* __restrict__ kw, u16* __restrict__ qn,
    u16* __restrict__ kn, u16* __restrict__ vt) {
  const int blk = blockIdx.x;
  const int tid = threadIdx.x;
  if (blk < 16384) {
    norm_body(q, qw, qn, 5, 0.08838834764831845f, blk, tid);
  } else if (blk < 20480) {
    norm_body(k, kw, kn, 3, 1.0f, blk - 16384, tid);
  } else {
    transv_body(v, vt, blk - 20480, tid);
  }
}

__global__ void __launch_bounds__(256, 3) attn_kernel(
    const u16* __restrict__ qn, const u16* __restrict__ kn,
    const u16* __restrict__ vt, float* __restrict__ out) {
  __shared__ char smem[32768];
  const int tid = threadIdx.x;
  const int w = tid >> 6;
  const int lane = tid & 63;
  const int c = lane & 15;
  const int g = lane >> 4;

  // 2048 blocks; XCD-locality remap; qt reversed so heavy blocks go first.
  const int p = blockIdx.x;
  const int bid = ((p & 7) << 8) + (p >> 3);
  const int qt = (bid & 127) ^ 127;
  const int hk = (bid >> 7) & 7;
  const int b = bid >> 10;
  const int i0 = qt * 16;
  const int h = hk * 4 + w;

  const u16* qb = qn + ((size_t)(b * HQ + h) * SEQ + i0) * DD;
  const u16* kbp = kn + (size_t)(b * HKV + hk) * SEQ * DD;
  const u16* vbp = vt + (size_t)(b * HKV + hk) * DD * SEQ;

  // Q fragments (MFMA B operand): col=c (query), k=g*8+j
  bf16x8 aq[4];
#pragma unroll
  for (int kt = 0; kt < 4; ++kt)
    aq[kt] = *reinterpret_cast<const bf16x8*>(qb + c * DD + kt * 32 + g * 8);

  int ks = i0 - WIN;
  ks = (ks < 0) ? 0 : (ks & ~63);
  const int ntl = (i0 + 16 - ks + 63) >> 6;   // 64-key tiles (<=9)

  const f32x2 vL2E = {1.44269504088896f, 1.44269504088896f};
  const f32x2 vmCE = {-43.2808512266689f, -43.2808512266689f};   // -CAP*log2e
  const f32x2 vmCTL = {-5.343315e-4f, -5.343315e-4f};            // -log2e/(3*CAP^2)

  // -------- staging (XOR-swizzled global source, linear LDS dest) ----
  auto stageK = [&](int kb, int bufoff) {   // 64 keys x 256B = 16KB
    char* dst = smem + bufoff;
#pragma unroll
    for (int ci = 0; ci < 4; ++ci) {
      const int call = w * 4 + ci;
      const int row = call * 4 + g;
      const int ch = c ^ (row & 7);
      gl16(kbp + (size_t)(kb + row) * DD + ch * 8, dst + call * 1024);
    }
  };
  auto stageV = [&](int kb, int bufoff) {   // [128 dims][128B=64 keys] = 16KB
    char* dst = smem + bufoff;
#pragma unroll
    for (int ci = 0; ci < 4; ++ci) {
      const int call = w * 4 + ci;
      const int vrow = call * 8 + (lane >> 3);
      const int vch = (lane & 7) ^ (vrow & 7);
      gl16(vbp + (size_t)vrow * SEQ + kb + vch * 8, dst + call * 1024);
    }
  };

  u32 ebuf[9][8];          // unnormalized exp, packed bf16; [tile][nt*2+pair]
  f32x2 lsum2 = {0.0f, 0.0f};

  // ---- pass 1: QK^T + cap + exp ONCE; keep e in registers ----
  stageK(ks, 0);
#pragma unroll
  for (int t = 0; t < 9; ++t) {
    if (t >= ntl) continue;                  // block-uniform
    const int kb = ks + t * 64;
    WAITV0();
    SBAR();
    if (t + 1 < ntl) stageK(kb + 64, ((t + 1) & 1) << 14);

    const char* kbuf = smem + ((t & 1) << 14);
    f32x4 sc[4] = {};
    __builtin_amdgcn_s_setprio(1);
#pragma unroll
    for (int nt = 0; nt < 4; ++nt) {
      const int jb = kb + nt * 16;
      if (jb > i0 + 15 || jb + 15 < i0 - WIN) continue;  // wave-uniform skip
      const int row = nt * 16 + c;
      const int sw = row & 7;
      const char* base = kbuf + row * 256;
#pragma unroll
      for (int kt = 0; kt < 4; ++kt) {
        const bf16x8 bk = *reinterpret_cast<const bf16x8*>(base + (((kt * 4 + g) ^ sw) << 4));
        sc[nt] = __builtin_amdgcn_mfma_f32_16x16x32_bf16(bk, aq[kt], sc[nt], 0, 0, 0);
      }
    }
    __builtin_amdgcn_s_setprio(0);

#pragma unroll
    for (int nt = 0; nt < 4; ++nt) {
      const int jb = kb + nt * 16;
      if (jb > i0 + 15 || jb + 15 < i0 - WIN) {
        ebuf[t][nt * 2] = 0;
        ebuf[t][nt * 2 + 1] = 0;
        continue;
      }
      const bool needmask = (jb + 15 > i0) || (jb < i0 + 15 - WIN);
      f32x2 lo = __builtin_shufflevector(sc[nt], sc[nt], 0, 1);
      f32x2 hi = __builtin_shufflevector(sc[nt], sc[nt], 2, 3);
      const f32x2 a0 = score2(lo, vL2E, vmCE, vmCTL);
      const f32x2 a1 = score2(hi, vL2E, vmCE, vmCTL);
      float e0 = __builtin_amdgcn_exp2f(a0[0]);
      float e1 = __builtin_amdgcn_exp2f(a0[1]);
      float e2 = __builtin_amdgcn_exp2f(a1[0]);
      float e3 = __builtin_amdgcn_exp2f(a1[1]);
      if (needmask) {
        const int difg = i0 + c - jb - g * 4;   // i - j for r=0
        e0 = ((u32)(difg - 0) <= WIN) ? e0 : 0.0f;
        e1 = ((u32)(difg - 1) <= WIN) ? e1 : 0.0f;
        e2 = ((u32)(difg - 2) <= WIN) ? e2 : 0.0f;
        e3 = ((u32)(difg - 3) <= WIN) ? e3 : 0.0f;
      }
      ebuf[t][nt * 2] = cvtpk(e0, e1);
      ebuf[t][nt * 2 + 1] = cvtpk(e2, e3);
      const f32x2 eA = {e0, e1};
      const f32x2 eB = {e2, e3};
      lsum2 = pk_add(lsum2, pk_add(eA, eB));
    }
  }
  WAITV0();
  SBAR();  // all waves done with pass-1 K buffers

  // pass-2 prologue V staging first; reduction hides under it
  stageV(ks, 0);

  float l = lsum2[0] + lsum2[1];
  l += __shfl_xor(l, 16);
  l += __shfl_xor(l, 32);
  const float ar = 1.06f / l;
  const f32x2 var2 = {ar, ar};
  const f32x2 vm003 = {-0.03f, -0.03f};

  f32x4 acc[8] = {};

  // ---- pass 2: V-only staging, clip stored e, PV ----
#pragma unroll
  for (int t = 0; t < 9; ++t) {
    if (t >= ntl) continue;
    const int kb = ks + t * 64;
    WAITV0();
    SBAR();
    if (t + 1 < ntl) stageV(kb + 64, ((t + 1) & 1) << 14);
    const char* ldsV = smem + ((t & 1) << 14);

#pragma unroll
    for (int k2 = 0; k2 < 2; ++k2) {
      const int jb2 = kb + k2 * 32;
      if (jb2 > i0 + 15 || jb2 + 31 < i0 - WIN) continue;  // dead 32-key half

      // clip: p = med3(1.06*e/l - 0.03, 0, 1), packed bf16
      u32 cw[4];
#pragma unroll
      for (int u = 0; u < 4; ++u) {
        const f32x2 ef = unpk(ebuf[t][k2 * 4 + u]);
        const f32x2 pr = pk_fma(ef, var2, vm003);
        cw[u] = cvtpk(__builtin_amdgcn_fmed3f(pr[0], 0.0f, 1.0f),
                      __builtin_amdgcn_fmed3f(pr[1], 0.0f, 1.0f));
      }

      // exchange: build PV A-fragment via permlane swaps (no LDS)
      union PU { bf16x8 v; u32 w4[4]; };
      PU pf;
      {
        u32 x0 = cw[0], y0 = cw[2];
        asm("v_permlane32_swap_b32 %0, %1" : "+v"(x0), "+v"(y0));
        asm("v_permlane16_swap_b32 %0, %1" : "+v"(x0), "+v"(y0));
        u32 x1 = cw[1], y1 = cw[3];
        asm("v_permlane32_swap_b32 %0, %1" : "+v"(x1), "+v"(y1));
        asm("v_permlane16_swap_b32 %0, %1" : "+v"(x1), "+v"(y1));
        pf.w4[0] = x0;
        pf.w4[1] = x1;
        pf.w4[2] = y0;
        pf.w4[3] = y1;
      }

      __builtin_amdgcn_s_setprio(1);
#pragma unroll
      for (int dt = 0; dt < 8; ++dt) {
        const int rv = dt * 16 + c;
        const bf16x8 bv = *reinterpret_cast<const bf16x8*>(
            ldsV + rv * 128 + (((k2 * 4 + g) ^ (rv & 7)) << 4));
        acc[dt] = __builtin_amdgcn_mfma_f32_16x16x32_bf16(pf.v, bv, acc[dt], 0, 0, 0);
      }
      __builtin_amdgcn_s_setprio(0);
    }
  }

  // epilogue: out[b][i][h][d] fp32; query = i0+4g+r, dim = 16dt+c
#pragma unroll
  for (int r = 0; r < 4; ++r) {
    const int i = i0 + g * 4 + r;
    float* op = out + (((size_t)b * SEQ + i) * HQ + h) * DD + c;
#pragma unroll
    for (int dt = 0; dt < 8; ++dt) op[dt * 16] = acc[dt][r];
  }
}

extern "C" void kernel_launch(void* const* d_in, const int* in_sizes, int n_in,
                              void* d_out, int out_size, void* d_ws, size_t ws_size,
                              hipStream_t stream) {
  const float* q = (const float*)d_in[0];
  const float* k = (const float*)d_in[1];
  const float* v = (const float*)d_in[2];
  const float* qw = (const float*)d_in[3];
  const float* kw = (const float*)d_in[4];
  float* out = (float*)d_out;

  u16* qn = (u16*)d_ws;                                  // [2][32][2048][128] bf16
  u16* kn = qn + (size_t)2 * HQ * SEQ * DD;              // [2][8][2048][128] bf16
  u16* vt = kn + (size_t)2 * HKV * SEQ * DD;             // [2][8][128][2048] bf16

  prep_kernel<<<20992, 256, 0, stream>>>(q, k, v, qw, kw, qn, kn, vt);
  attn_kernel<<<2048, 256, 0, stream>>>(qn, kn, vt, out);
}

// Round 9
// 86.419 us; speedup vs baseline: 2.6492x; 1.0825x over previous
//
#include <hip/hip_runtime.h>

#define SEQ 2048
#define DD 128
#define HQ 32
#define HKV 8
#define WIN 512

typedef unsigned short u16;
typedef unsigned int u32;
typedef __attribute__((ext_vector_type(8))) short bf16x8;
typedef __attribute__((ext_vector_type(4))) float f32x4;
typedef __attribute__((ext_vector_type(2))) float f32x2;

#define SBAR() asm volatile("s_barrier" ::: "memory")
#define WAITV0() asm volatile("s_waitcnt vmcnt(0)" ::: "memory")

__device__ __forceinline__ u16 f2bf(float f) {
  u32 u = __builtin_bit_cast(u32, f);
  u += 0x7FFFu + ((u >> 16) & 1u);
  return (u16)(u >> 16);
}

__device__ __forceinline__ void gl16(const void* g, void* l) {
  __builtin_amdgcn_global_load_lds(
      (const __attribute__((address_space(1))) void*)g,
      (__attribute__((address_space(3))) void*)l, 16, 0, 0);
}

__device__ __forceinline__ u32 cvtpk(float lo, float hi) {
  u32 r;
  asm("v_cvt_pk_bf16_f32 %0, %1, %2" : "=v"(r) : "v"(lo), "v"(hi));
  return r;
}

__device__ __forceinline__ f32x2 pk_mul(f32x2 a, f32x2 b) {
  f32x2 d;
  asm("v_pk_mul_f32 %0, %1, %2" : "=v"(d) : "v"(a), "v"(b));
  return d;
}
__device__ __forceinline__ f32x2 pk_fma(f32x2 a, f32x2 b, f32x2 c) {
  f32x2 d;
  asm("v_pk_fma_f32 %0, %1, %2, %3" : "=v"(d) : "v"(a), "v"(b), "v"(c));
  return d;
}
__device__ __forceinline__ f32x2 pk_add(f32x2 a, f32x2 b) {
  f32x2 d;
  asm("v_pk_add_f32 %0, %1, %2" : "=v"(d) : "v"(a), "v"(b));
  return d;
}

// exp2 argument for capped score pair: x*log2e - C_E - (C_T*log2e)*x^3
__device__ __forceinline__ f32x2 score2(f32x2 x, f32x2 vL2E, f32x2 vmCE, f32x2 vmCTL) {
  f32x2 x2 = pk_mul(x, x);
  f32x2 a1 = pk_fma(x, vL2E, vmCE);
  f32x2 b1 = pk_mul(x2, vmCTL);
  return pk_fma(b1, x, a1);
}

// unpack 2 bf16 (packed u32) -> f32x2
__device__ __forceinline__ f32x2 unpk(u32 wv) {
  f32x2 r;
  r[0] = __builtin_bit_cast(float, wv << 16);
  r[1] = __builtin_bit_cast(float, wv & 0xFFFF0000u);
  return r;
}

// GroupRMSNorm + weight + bf16 + repack to [b][h][s][d]  (K only now)
__device__ __forceinline__ void norm_body(
    const float* __restrict__ x, const float* __restrict__ w,
    u16* __restrict__ o, int hshift, int blk, int tid) {
  const int lane = tid & 63;
  const int wv = tid >> 6;
  const int sub = lane >> 5;
  const int l5 = lane & 31;
  const int rid = blk * 8 + wv * 2 + sub;   // flattened (b,s,h)
  const int H = 1 << hshift;
  const int hh = rid & (H - 1);
  const int s = (rid >> hshift) & (SEQ - 1);
  const int b = rid >> (hshift + 11);
  const float4 xv = *(reinterpret_cast<const float4*>(x + (size_t)rid * DD) + l5);
  float ssq = xv.x * xv.x + xv.y * xv.y + xv.z * xv.z + xv.w * xv.w;
  ssq += __shfl_xor(ssq, 1);
  ssq += __shfl_xor(ssq, 2);
  ssq += __shfl_xor(ssq, 4);
  ssq += __shfl_xor(ssq, 8);
  ssq += __shfl_xor(ssq, 16);
  const float inv = rsqrtf(ssq * (1.0f / 128.0f) + 1e-5f);
  const float4 wv4 = *(reinterpret_cast<const float4*>(w + hh * DD) + l5);
  const u16 o0 = f2bf(xv.x * inv * wv4.x);
  const u16 o1 = f2bf(xv.y * inv * wv4.y);
  const u16 o2 = f2bf(xv.z * inv * wv4.z);
  const u16 o3 = f2bf(xv.w * inv * wv4.w);
  const size_t oo = (((size_t)b * H + hh) * SEQ + s) * DD + l5 * 4;
  uint2 pk;
  pk.x = (u32)o0 | ((u32)o1 << 16);
  pk.y = (u32)o2 | ((u32)o3 << 16);
  *reinterpret_cast<uint2*>(o + oo) = pk;
}

// V: fp32 [b][s][h][d] -> bf16 transposed [b][h][d][s]
__device__ __forceinline__ void transv_body(
    const float* __restrict__ v, u16* __restrict__ vt, int bid, int t) {
  const int st = bid & 31;
  const int h = (bid >> 5) & 7;
  const int b = bid >> 8;
  const int sbase = st * 64;
  const int d = t & 127;
  const int sch = (t >> 7) * 32;
  const size_t oo = (((size_t)(b * HKV + h)) * DD + d) * SEQ + sbase + sch;
#pragma unroll
  for (int q8 = 0; q8 < 4; ++q8) {
    uint4 o;
    u32 c[4];
#pragma unroll
    for (int p = 0; p < 4; ++p) {
      const int ss0 = q8 * 8 + p * 2;
      const int s0 = sbase + sch + ss0;
      const float a0 = v[((size_t)(b * SEQ + s0) * HKV + h) * DD + d];
      const float a1 = v[((size_t)(b * SEQ + s0 + 1) * HKV + h) * DD + d];
      c[p] = (u32)f2bf(a0) | ((u32)f2bf(a1) << 16);
    }
    o.x = c[0]; o.y = c[1]; o.z = c[2]; o.w = c[3];
    *reinterpret_cast<uint4*>(vt + oo + q8 * 8) = o;
  }
}

__global__ void __launch_bounds__(256) prep_kernel(
    const float* __restrict__ k, const float* __restrict__ v,
    const float* __restrict__ kw, u16* __restrict__ kn, u16* __restrict__ vt) {
  const int blk = blockIdx.x;
  const int tid = threadIdx.x;
  if (blk < 4096) {
    norm_body(k, kw, kn, 3, blk, tid);
  } else {
    transv_body(v, vt, blk - 4096, tid);
  }
}

__global__ void __launch_bounds__(256, 3) attn_kernel(
    const float* __restrict__ q32, const float* __restrict__ qw,
    const u16* __restrict__ kn, const u16* __restrict__ vt,
    float* __restrict__ out) {
  __shared__ char smem[32768];
  const int tid = threadIdx.x;
  const int w = tid >> 6;
  const int lane = tid & 63;
  const int c = lane & 15;
  const int g = lane >> 4;

  // 2048 blocks; XCD-locality remap; qt reversed so heavy blocks go first.
  const int p = blockIdx.x;
  const int bid = ((p & 7) << 8) + (p >> 3);
  const int qt = (bid & 127) ^ 127;
  const int hk = (bid >> 7) & 7;
  const int b = bid >> 10;
  const int i0 = qt * 16;
  const int h = hk * 4 + w;

  const u16* kbp = kn + (size_t)(b * HKV + hk) * SEQ * DD;
  const u16* vbp = vt + (size_t)(b * HKV + hk) * DD * SEQ;

  int ks = i0 - WIN;
  ks = (ks < 0) ? 0 : (ks & ~63);
  const int ntl = (i0 + 16 - ks + 63) >> 6;   // 64-key tiles (<=9)

  // -------- staging (XOR-swizzled global source, linear LDS dest) ----
  auto stageK = [&](int kb, int bufoff) {   // 64 keys x 256B = 16KB
    char* dst = smem + bufoff;
#pragma unroll
    for (int ci = 0; ci < 4; ++ci) {
      const int call = w * 4 + ci;
      const int row = call * 4 + g;
      const int ch = c ^ (row & 7);
      gl16(kbp + (size_t)(kb + row) * DD + ch * 8, dst + call * 1024);
    }
  };
  auto stageV = [&](int kb, int bufoff) {   // [128 dims][128B=64 keys] = 16KB
    char* dst = smem + bufoff;
#pragma unroll
    for (int ci = 0; ci < 4; ++ci) {
      const int call = w * 4 + ci;
      const int vrow = call * 8 + (lane >> 3);
      const int vch = (lane & 7) ^ (vrow & 7);
      gl16(vbp + (size_t)vrow * SEQ + kb + vch * 8, dst + call * 1024);
    }
  };

  // kick off first K tile before Q-norm; its latency hides under the norm
  stageK(ks, 0);

  // ---- fused Q GroupRMSNorm -> bf16 fragments (MFMA B operand) ----
  // lane (c,g): row i0+c, cols {kt*32 + g*8 .. +7}
  union AQ { bf16x8 v; u32 w4[4]; };
  AQ aq[4];
  {
    const float* qf = q32 + (((size_t)b * SEQ + i0 + c) * HQ + h) * DD;
    const float* wf = qw + h * DD;
    float xv[4][8];
    float ss = 0.0f;
#pragma unroll
    for (int kt = 0; kt < 4; ++kt) {
      const float4 a0 = *reinterpret_cast<const float4*>(qf + kt * 32 + g * 8);
      const float4 a1 = *reinterpret_cast<const float4*>(qf + kt * 32 + g * 8 + 4);
      xv[kt][0] = a0.x; xv[kt][1] = a0.y; xv[kt][2] = a0.z; xv[kt][3] = a0.w;
      xv[kt][4] = a1.x; xv[kt][5] = a1.y; xv[kt][6] = a1.z; xv[kt][7] = a1.w;
      ss = fmaf(a0.x, a0.x, ss); ss = fmaf(a0.y, a0.y, ss);
      ss = fmaf(a0.z, a0.z, ss); ss = fmaf(a0.w, a0.w, ss);
      ss = fmaf(a1.x, a1.x, ss); ss = fmaf(a1.y, a1.y, ss);
      ss = fmaf(a1.z, a1.z, ss); ss = fmaf(a1.w, a1.w, ss);
    }
    ss += __shfl_xor(ss, 16);
    ss += __shfl_xor(ss, 32);
    const float inv = rsqrtf(ss * (1.0f / 128.0f) + 1e-5f) * 0.08838834764831845f;
#pragma unroll
    for (int kt = 0; kt < 4; ++kt) {
      const float4 w0 = *reinterpret_cast<const float4*>(wf + kt * 32 + g * 8);
      const float4 w1 = *reinterpret_cast<const float4*>(wf + kt * 32 + g * 8 + 4);
      aq[kt].w4[0] = cvtpk(xv[kt][0] * inv * w0.x, xv[kt][1] * inv * w0.y);
      aq[kt].w4[1] = cvtpk(xv[kt][2] * inv * w0.z, xv[kt][3] * inv * w0.w);
      aq[kt].w4[2] = cvtpk(xv[kt][4] * inv * w1.x, xv[kt][5] * inv * w1.y);
      aq[kt].w4[3] = cvtpk(xv[kt][6] * inv * w1.z, xv[kt][7] * inv * w1.w);
    }
  }

  const f32x2 vL2E = {1.44269504088896f, 1.44269504088896f};
  const f32x2 vmCE = {-43.2808512266689f, -43.2808512266689f};   // -CAP*log2e
  const f32x2 vmCTL = {-5.343315e-4f, -5.343315e-4f};            // -log2e/(3*CAP^2)

  u32 ebuf[9][8];          // unnormalized exp, packed bf16; [tile][nt*2+pair]
  f32x2 lsum2 = {0.0f, 0.0f};

  // ---- pass 1: QK^T + cap + exp ONCE; keep e in registers ----
#pragma unroll
  for (int t = 0; t < 9; ++t) {
    if (t >= ntl) continue;                  // block-uniform
    const int kb = ks + t * 64;
    WAITV0();
    SBAR();
    if (t + 1 < ntl) stageK(kb + 64, ((t + 1) & 1) << 14);

    const char* kbuf = smem + ((t & 1) << 14);
    f32x4 sc[4] = {};
    __builtin_amdgcn_s_setprio(1);
#pragma unroll
    for (int nt = 0; nt < 4; ++nt) {
      const int jb = kb + nt * 16;
      if (jb > i0 + 15 || jb + 15 < i0 - WIN) continue;  // wave-uniform skip
      const int row = nt * 16 + c;
      const int sw = row & 7;
      const char* base = kbuf + row * 256;
#pragma unroll
      for (int kt = 0; kt < 4; ++kt) {
        const bf16x8 bk = *reinterpret_cast<const bf16x8*>(base + (((kt * 4 + g) ^ sw) << 4));
        sc[nt] = __builtin_amdgcn_mfma_f32_16x16x32_bf16(bk, aq[kt].v, sc[nt], 0, 0, 0);
      }
    }
    __builtin_amdgcn_s_setprio(0);

#pragma unroll
    for (int nt = 0; nt < 4; ++nt) {
      const int jb = kb + nt * 16;
      if (jb > i0 + 15 || jb + 15 < i0 - WIN) {
        ebuf[t][nt * 2] = 0;
        ebuf[t][nt * 2 + 1] = 0;
        continue;
      }
      const bool needmask = (jb + 15 > i0) || (jb < i0 + 15 - WIN);
      f32x2 lo = __builtin_shufflevector(sc[nt], sc[nt], 0, 1);
      f32x2 hi = __builtin_shufflevector(sc[nt], sc[nt], 2, 3);
      const f32x2 a0 = score2(lo, vL2E, vmCE, vmCTL);
      const f32x2 a1 = score2(hi, vL2E, vmCE, vmCTL);
      float e0 = __builtin_amdgcn_exp2f(a0[0]);
      float e1 = __builtin_amdgcn_exp2f(a0[1]);
      float e2 = __builtin_amdgcn_exp2f(a1[0]);
      float e3 = __builtin_amdgcn_exp2f(a1[1]);
      if (needmask) {
        const int difg = i0 + c - jb - g * 4;   // i - j for r=0
        e0 = ((u32)(difg - 0) <= WIN) ? e0 : 0.0f;
        e1 = ((u32)(difg - 1) <= WIN) ? e1 : 0.0f;
        e2 = ((u32)(difg - 2) <= WIN) ? e2 : 0.0f;
        e3 = ((u32)(difg - 3) <= WIN) ? e3 : 0.0f;
      }
      ebuf[t][nt * 2] = cvtpk(e0, e1);
      ebuf[t][nt * 2 + 1] = cvtpk(e2, e3);
      const f32x2 eA = {e0, e1};
      const f32x2 eB = {e2, e3};
      lsum2 = pk_add(lsum2, pk_add(eA, eB));
    }
  }
  WAITV0();
  SBAR();  // all waves done with pass-1 K buffers

  // pass-2 prologue V staging first; reduction hides under it
  stageV(ks, 0);

  float l = lsum2[0] + lsum2[1];
  l += __shfl_xor(l, 16);
  l += __shfl_xor(l, 32);
  const float ar = 1.06f / l;
  const f32x2 var2 = {ar, ar};
  const f32x2 vm003 = {-0.03f, -0.03f};

  f32x4 acc[8] = {};

  // ---- pass 2: V-only staging, clip stored e, PV ----
#pragma unroll
  for (int t = 0; t < 9; ++t) {
    if (t >= ntl) continue;
    const int kb = ks + t * 64;
    WAITV0();
    SBAR();
    if (t + 1 < ntl) stageV(kb + 64, ((t + 1) & 1) << 14);
    const char* ldsV = smem + ((t & 1) << 14);

#pragma unroll
    for (int k2 = 0; k2 < 2; ++k2) {
      const int jb2 = kb + k2 * 32;
      if (jb2 > i0 + 15 || jb2 + 31 < i0 - WIN) continue;  // dead 32-key half

      // clip: p = med3(1.06*e/l - 0.03, 0, 1), packed bf16
      u32 cw[4];
#pragma unroll
      for (int u = 0; u < 4; ++u) {
        const f32x2 ef = unpk(ebuf[t][k2 * 4 + u]);
        const f32x2 pr = pk_fma(ef, var2, vm003);
        cw[u] = cvtpk(__builtin_amdgcn_fmed3f(pr[0], 0.0f, 1.0f),
                      __builtin_amdgcn_fmed3f(pr[1], 0.0f, 1.0f));
      }

      // exchange: build PV A-fragment via permlane swaps (no LDS)
      union PU { bf16x8 v; u32 w4[4]; };
      PU pf;
      {
        u32 x0 = cw[0], y0 = cw[2];
        asm("v_permlane32_swap_b32 %0, %1" : "+v"(x0), "+v"(y0));
        asm("v_permlane16_swap_b32 %0, %1" : "+v"(x0), "+v"(y0));
        u32 x1 = cw[1], y1 = cw[3];
        asm("v_permlane32_swap_b32 %0, %1" : "+v"(x1), "+v"(y1));
        asm("v_permlane16_swap_b32 %0, %1" : "+v"(x1), "+v"(y1));
        pf.w4[0] = x0;
        pf.w4[1] = x1;
        pf.w4[2] = y0;
        pf.w4[3] = y1;
      }

      __builtin_amdgcn_s_setprio(1);
#pragma unroll
      for (int dt = 0; dt < 8; ++dt) {
        const int rv = dt * 16 + c;
        const bf16x8 bv = *reinterpret_cast<const bf16x8*>(
            ldsV + rv * 128 + (((k2 * 4 + g) ^ (rv & 7)) << 4));
        acc[dt] = __builtin_amdgcn_mfma_f32_16x16x32_bf16(pf.v, bv, acc[dt], 0, 0, 0);
      }
      __builtin_amdgcn_s_setprio(0);
    }
  }

  // epilogue: out[b][i][h][d] fp32; query = i0+4g+r, dim = 16dt+c
#pragma unroll
  for (int r = 0; r < 4; ++r) {
    const int i = i0 + g * 4 + r;
    float* op = out + (((size_t)b * SEQ + i) * HQ + h) * DD + c;
#pragma unroll
    for (int dt = 0; dt < 8; ++dt) op[dt * 16] = acc[dt][r];
  }
}

extern "C" void kernel_launch(void* const* d_in, const int* in_sizes, int n_in,
                              void* d_out, int out_size, void* d_ws, size_t ws_size,
                              hipStream_t stream) {
  const float* q = (const float*)d_in[0];
  const float* k = (const float*)d_in[1];
  const float* v = (const float*)d_in[2];
  const float* qw = (const float*)d_in[3];
  const float* kw = (const float*)d_in[4];
  float* out = (float*)d_out;

  u16* kn = (u16*)d_ws;                                  // [2][8][2048][128] bf16
  u16* vt = kn + (size_t)2 * HKV * SEQ * DD;             // [2][8][128][2048] bf16

  prep_kernel<<<4608, 256, 0, stream>>>(k, v, kw, kn, vt);
  attn_kernel<<<2048, 256, 0, stream>>>(q, qw, kn, vt, out);
}